// Round 5
// baseline (356.578 us; speedup 1.0000x reference)
//
#include <hip/hip_runtime.h>

#define BB 2048
#define TT 256
#define DA 20
#define DZ 4
#define KK 3
#define NC 64      // chunks per sequence
#define CL 4       // chunk length (NC*CL == TT)
#define NCH (BB*NC)
#define QQ 0.08f
#define RINV (1.0f/0.03f)

// sym10 layout: [0]=00 [1]=01 [2]=02 [3]=03 [4]=11 [5]=12 [6]=13 [7]=22 [8]=23 [9]=33
__device__ __forceinline__ void sym_expand(const float* s, float* f){
  f[0]=s[0];  f[1]=s[1];  f[2]=s[2];  f[3]=s[3];
  f[4]=s[1];  f[5]=s[4];  f[6]=s[5];  f[7]=s[6];
  f[8]=s[2];  f[9]=s[5];  f[10]=s[7]; f[11]=s[8];
  f[12]=s[3]; f[13]=s[6]; f[14]=s[8]; f[15]=s[9];
}
__device__ __forceinline__ void sym_from_full(const float* F, float* s){
  s[0]=F[0]; s[1]=0.5f*(F[1]+F[4]); s[2]=0.5f*(F[2]+F[8]); s[3]=0.5f*(F[3]+F[12]);
  s[4]=F[5]; s[5]=0.5f*(F[6]+F[9]); s[6]=0.5f*(F[7]+F[13]);
  s[7]=F[10]; s[8]=0.5f*(F[11]+F[14]); s[9]=F[15];
}

__device__ __forceinline__ void inv4(const float* m, float* b){
  float s0 = m[0]*m[5]  - m[4]*m[1];
  float s1 = m[0]*m[6]  - m[4]*m[2];
  float s2 = m[0]*m[7]  - m[4]*m[3];
  float s3 = m[1]*m[6]  - m[5]*m[2];
  float s4 = m[1]*m[7]  - m[5]*m[3];
  float s5 = m[2]*m[7]  - m[6]*m[3];
  float c5 = m[10]*m[15] - m[14]*m[11];
  float c4 = m[9]*m[15]  - m[13]*m[11];
  float c3 = m[9]*m[14]  - m[13]*m[10];
  float c2 = m[8]*m[15]  - m[12]*m[11];
  float c1 = m[8]*m[14]  - m[12]*m[10];
  float c0 = m[8]*m[13]  - m[12]*m[9];
  float det = s0*c5 - s1*c4 + s2*c3 + s3*c2 - s4*c1 + s5*c0;
  float id = 1.0f/det;
  b[0]  = ( m[5]*c5  - m[6]*c4  + m[7]*c3 )*id;
  b[1]  = (-m[1]*c5  + m[2]*c4  - m[3]*c3 )*id;
  b[2]  = ( m[13]*s5 - m[14]*s4 + m[15]*s3)*id;
  b[3]  = (-m[9]*s5  + m[10]*s4 - m[11]*s3)*id;
  b[4]  = (-m[4]*c5  + m[6]*c2  - m[7]*c1 )*id;
  b[5]  = ( m[0]*c5  - m[2]*c2  + m[3]*c1 )*id;
  b[6]  = (-m[12]*s5 + m[14]*s2 - m[15]*s1)*id;
  b[7]  = ( m[8]*s5  - m[10]*s2 + m[11]*s1)*id;
  b[8]  = ( m[4]*c4  - m[5]*c2  + m[7]*c0 )*id;
  b[9]  = (-m[0]*c4  + m[1]*c2  - m[3]*c0 )*id;
  b[10] = ( m[12]*s4 - m[13]*s2 + m[15]*s0)*id;
  b[11] = (-m[8]*s4  + m[9]*s2  - m[11]*s0)*id;
  b[12] = (-m[4]*c3  + m[5]*c1  - m[6]*c0 )*id;
  b[13] = ( m[0]*c3  - m[1]*c1  + m[2]*c0 )*id;
  b[14] = (-m[12]*s3 + m[13]*s1 - m[14]*s0)*id;
  b[15] = ( m[8]*s3  - m[9]*s1  + m[10]*s0)*id;
}

__device__ __forceinline__ void mm4(const float* A, const float* Bm, float* C){
  #pragma unroll
  for (int i=0;i<4;i++){
    #pragma unroll
    for (int j=0;j<4;j++){
      float acc = A[i*4+0]*Bm[0*4+j];
      acc = fmaf(A[i*4+1], Bm[1*4+j], acc);
      acc = fmaf(A[i*4+2], Bm[2*4+j], acc);
      acc = fmaf(A[i*4+3], Bm[3*4+j], acc);
      C[i*4+j] = acc;
    }
  }
}
__device__ __forceinline__ void mm4_bt(const float* A, const float* Bm, float* C){
  #pragma unroll
  for (int i=0;i<4;i++){
    #pragma unroll
    for (int j=0;j<4;j++){
      float acc = A[i*4+0]*Bm[j*4+0];
      acc = fmaf(A[i*4+1], Bm[j*4+1], acc);
      acc = fmaf(A[i*4+2], Bm[j*4+2], acc);
      acc = fmaf(A[i*4+3], Bm[j*4+3], acc);
      C[i*4+j] = acc;
    }
  }
}
__device__ __forceinline__ void mm4_at(const float* A, const float* Bm, float* C){
  #pragma unroll
  for (int i=0;i<4;i++){
    #pragma unroll
    for (int j=0;j<4;j++){
      float acc = A[0*4+i]*Bm[0*4+j];
      acc = fmaf(A[1*4+i], Bm[1*4+j], acc);
      acc = fmaf(A[2*4+i], Bm[2*4+j], acc);
      acc = fmaf(A[3*4+i], Bm[3*4+j], acc);
      C[i*4+j] = acc;
    }
  }
}
__device__ __forceinline__ void mv4(const float* M, const float* v, float* o){
  #pragma unroll
  for (int i=0;i<4;i++)
    o[i] = fmaf(M[i*4+3],v[3],fmaf(M[i*4+2],v[2],fmaf(M[i*4+1],v[1],M[i*4+0]*v[0])));
}
__device__ __forceinline__ void mv4_t(const float* M, const float* v, float* o){
  #pragma unroll
  for (int i=0;i<4;i++)
    o[i] = fmaf(M[12+i],v[3],fmaf(M[8+i],v[2],fmaf(M[4+i],v[1],M[i]*v[0])));
}

// plane index: buffers are float4 planes [p][c][b] -> coalesced over b (lane dim)
__device__ __forceinline__ size_t PIDX(int p, int c, int b){
  return ((size_t)p*NC + c)*BB + b;
}

// mixing from prefetched registers: av[5] float4 = a[b][t][0..19]; l0..l2 = logits
__device__ __forceinline__ void mix_from_regs(
    const float4* avq, float l0, float l1, float l2,
    const float* sA, const float* sC,
    float* Am, float* G, float* w)
{
  float mx = fmaxf(l0, fmaxf(l1,l2));
  float e0=expf(l0-mx), e1=expf(l1-mx), e2=expf(l2-mx);
  float is = 1.0f/(e0+e1+e2);
  float a0=e0*is, a1=e1*is, a2=e2*is;
  #pragma unroll
  for (int c=0;c<16;c++) Am[c] = fmaf(a0,sA[c],fmaf(a1,sA[16+c],a2*sA[32+c]));
  float av[20]={avq[0].x,avq[0].y,avq[0].z,avq[0].w, avq[1].x,avq[1].y,avq[1].z,avq[1].w,
                avq[2].x,avq[2].y,avq[2].z,avq[2].w, avq[3].x,avq[3].y,avq[3].z,avq[3].w,
                avq[4].x,avq[4].y,avq[4].z,avq[4].w};
  #pragma unroll
  for (int c=0;c<10;c++) G[c]=0.f;
  w[0]=0.f;w[1]=0.f;w[2]=0.f;w[3]=0.f;
  #pragma unroll
  for (int d=0; d<DA; d++){
    float ad = av[d];
    float c0 = fmaf(a0, sC[d*4+0], fmaf(a1, sC[80+d*4+0], a2*sC[160+d*4+0]));
    float c1 = fmaf(a0, sC[d*4+1], fmaf(a1, sC[80+d*4+1], a2*sC[160+d*4+1]));
    float c2 = fmaf(a0, sC[d*4+2], fmaf(a1, sC[80+d*4+2], a2*sC[160+d*4+2]));
    float c3 = fmaf(a0, sC[d*4+3], fmaf(a1, sC[80+d*4+3], a2*sC[160+d*4+3]));
    w[0]=fmaf(c0,ad,w[0]); w[1]=fmaf(c1,ad,w[1]); w[2]=fmaf(c2,ad,w[2]); w[3]=fmaf(c3,ad,w[3]);
    G[0]=fmaf(c0,c0,G[0]); G[1]=fmaf(c0,c1,G[1]); G[2]=fmaf(c0,c2,G[2]); G[3]=fmaf(c0,c3,G[3]);
    G[4]=fmaf(c1,c1,G[4]); G[5]=fmaf(c1,c2,G[5]); G[6]=fmaf(c1,c3,G[6]);
    G[7]=fmaf(c2,c2,G[7]); G[8]=fmaf(c2,c3,G[8]);
    G[9]=fmaf(c3,c3,G[9]);
  }
  #pragma unroll
  for (int c=0;c<10;c++) G[c]*=RINV;
  #pragma unroll
  for (int c=0;c<4;c++)  w[c]*=RINV;
}

// filter element: Phi=(I+qG)^-1; A*=Phi A; b*=q Phi w; C*=q Phi; eta*=A^T Phi w; J*=A^T Phi G A
__device__ __forceinline__ void elem_build(const float* Am, const float* G, const float* w,
    float* Ae, float* be, float* Ce, float* he, float* Je)
{
  float Gf[16]; sym_expand(G,Gf);
  float N[16];
  #pragma unroll
  for (int i=0;i<16;i++) N[i] = QQ*Gf[i];
  N[0]+=1.f; N[5]+=1.f; N[10]+=1.f; N[15]+=1.f;
  float Phi[16]; inv4(N,Phi);
  mm4(Phi, Am, Ae);
  float Pw[4]; mv4(Phi, w, Pw);
  #pragma unroll
  for (int i=0;i<4;i++) be[i]=QQ*Pw[i];
  mv4_t(Am, Pw, he);
  float PhiG[16]; mm4(Phi, Gf, PhiG);
  float U[16]; mm4_at(Am, PhiG, U);
  float Jf[16]; mm4(U, Am, Jf);
  sym_from_full(Jf, Je);
  float Cf[16];
  #pragma unroll
  for (int i=0;i<16;i++) Cf[i]=QQ*Phi[i];
  sym_from_full(Cf, Ce);
}

// running(earlier) = running ⊗ e(later)
__device__ __forceinline__ void compose(float* Ar, float* br, float* Cr, float* hr, float* Jr,
    const float* Ae, const float* be, const float* Ce, const float* he, const float* Je)
{
  float Crf[16]; sym_expand(Cr,Crf);
  float Jef[16]; sym_expand(Je,Jef);
  float N[16]; mm4(Crf,Jef,N);
  N[0]+=1.f; N[5]+=1.f; N[10]+=1.f; N[15]+=1.f;
  float E[16]; inv4(N,E);
  float EA[16]; mm4(E,Ar,EA);
  float Anew[16]; mm4(Ae,EA,Anew);
  float t1[4]; mv4(Crf,he,t1);
  #pragma unroll
  for (int i=0;i<4;i++) t1[i]+=br[i];
  float t2[4]; mv4(E,t1,t2);
  float bnew[4]; mv4(Ae,t2,bnew);
  #pragma unroll
  for (int i=0;i<4;i++) bnew[i]+=be[i];
  float EC[16]; mm4(E,Crf,EC);
  float AEC[16]; mm4(Ae,EC,AEC);
  float Cfull[16]; mm4_bt(AEC,Ae,Cfull);
  float Cnew[10]; sym_from_full(Cfull,Cnew);
  #pragma unroll
  for (int i=0;i<10;i++) Cnew[i]+=Ce[i];
  float v[4]; mv4(Jef,br,v);
  #pragma unroll
  for (int i=0;i<4;i++) v[i]=he[i]-v[i];
  float Ev[4]; mv4_t(E,v,Ev);
  float hnew[4]; mv4_t(Ar,Ev,hnew);
  #pragma unroll
  for (int i=0;i<4;i++) hnew[i]+=hr[i];
  float EtJ[16]; mm4_at(E,Jef,EtJ);
  float AtEtJ[16]; mm4_at(Ar,EtJ,AtEtJ);
  float Jfull[16]; mm4(AtEtJ,Ar,Jfull);
  float Jnew[10]; sym_from_full(Jfull,Jnew);
  #pragma unroll
  for (int i=0;i<10;i++) Jnew[i]+=Jr[i];
  #pragma unroll
  for (int i=0;i<16;i++) Ar[i]=Anew[i];
  #pragma unroll
  for (int i=0;i<4;i++){ br[i]=bnew[i]; hr[i]=hnew[i]; }
  #pragma unroll
  for (int i=0;i<10;i++){ Cr[i]=Cnew[i]; Jr[i]=Jnew[i]; }
}

// apply element to state (m,S)
__device__ __forceinline__ void elem_apply(const float* Ae, const float* be, const float* Ce,
    const float* he, const float* Je, float* m, float* S)
{
  float Pf[16]; sym_expand(S,Pf);
  float Jf[16]; sym_expand(Je,Jf);
  float N[16]; mm4(Pf,Jf,N);
  N[0]+=1.f; N[5]+=1.f; N[10]+=1.f; N[15]+=1.f;
  float T[16]; inv4(N,T);
  float t1[4]; mv4(Pf,he,t1);
  #pragma unroll
  for (int i=0;i<4;i++) t1[i]+=m[i];
  float t2[4]; mv4(T,t1,t2);
  float mn[4]; mv4(Ae,t2,mn);
  #pragma unroll
  for (int i=0;i<4;i++) mn[i]+=be[i];
  float TP[16]; mm4(T,Pf,TP);
  float ATP[16]; mm4(Ae,TP,ATP);
  float Pn[16]; mm4_bt(ATP,Ae,Pn);
  float Sn[10]; sym_from_full(Pn,Sn);
  #pragma unroll
  for (int i=0;i<10;i++) S[i]=Sn[i]+Ce[i];
  #pragma unroll
  for (int i=0;i<4;i++) m[i]=mn[i];
}

// smoother per-step element: D = Mj A1^T inv(Pc1); e = pzj - D (A1 pzj); F = Mj - D Pc1 D^T
__device__ __forceinline__ void sm_build(const float* A1, const float* Pc1,
    const float* Mj, const float* pzj, float* D, float* e, float* F)
{
  float Pcf[16]; sym_expand(Pc1,Pcf);
  float E[16]; inv4(Pcf,E);
  float Mf[16]; sym_expand(Mj,Mf);
  float MB[16]; mm4_bt(Mf,A1,MB);
  mm4(MB,E,D);
  float zh[4]; mv4(A1,pzj,zh);
  float Dzh[4]; mv4(D,zh,Dzh);
  #pragma unroll
  for (int i=0;i<4;i++) e[i]=pzj[i]-Dzh[i];
  float U[16]; mm4(D,Pcf,U);
  float W[16]; mm4_bt(U,D,W);
  float Ws[10]; sym_from_full(W,Ws);
  #pragma unroll
  for (int i=0;i<10;i++) F[i]=Mj[i]-Ws[i];
}

// apply smoother element: z' = D z + e; S' = D S D^T + F
__device__ __forceinline__ void sm_apply(const float* D, const float* e, const float* F,
    float* z, float* S)
{
  float zn[4]; mv4(D,z,zn);
  #pragma unroll
  for (int i=0;i<4;i++) z[i]=zn[i]+e[i];
  float Sf[16]; sym_expand(S,Sf);
  float U[16]; mm4(D,Sf,U);
  float W[16]; mm4_bt(U,D,W);
  float Sn[10]; sym_from_full(W,Sn);
  #pragma unroll
  for (int i=0;i<10;i++) S[i]=Sn[i]+F[i];
}

// ================= Kernel 1: per-chunk filter element composition =================
__global__ __launch_bounds__(256) void k_fchunk(
    const float* __restrict__ a, const float* __restrict__ logits,
    const float* __restrict__ Abase, const float* __restrict__ Cbase,
    float4* __restrict__ chel)
{
  __shared__ float sA[KK*16];
  __shared__ float sC[KK*DA*DZ];
  for (int i=threadIdx.x;i<KK*16;i+=256) sA[i]=Abase[i];
  for (int i=threadIdx.x;i<KK*DA*DZ;i+=256) sC[i]=Cbase[i];
  __syncthreads();
  int tid = blockIdx.x*256+threadIdx.x;
  int b = tid & (BB-1);
  int c = tid >> 11;
  // hoist logits for whole chunk: CL*3 = 12 floats = 3 float4 (16B-aligned)
  const float4* lgp = (const float4*)(logits + ((size_t)b*TT + c*CL)*KK);
  float4 lq0=lgp[0], lq1=lgp[1], lq2=lgp[2];
  float lgf[12]={lq0.x,lq0.y,lq0.z,lq0.w, lq1.x,lq1.y,lq1.z,lq1.w, lq2.x,lq2.y,lq2.z,lq2.w};
  // a double-buffer
  const float4* ap = (const float4*)(a + ((size_t)b*TT + c*CL)*DA);
  float4 av[5], avn[5];
  #pragma unroll
  for (int i=0;i<5;i++) av[i]=ap[i];

  float Ar[16], br[4], Cr[10], hr[4], Jr[10];
  #pragma unroll 1
  for (int s=0;s<CL;s++){
    if (s+1<CL){
      #pragma unroll
      for (int i=0;i<5;i++) avn[i]=ap[(s+1)*5+i];
    }
    float Am[16], G[10], w[4];
    mix_from_regs(av, lgf[s*3+0], lgf[s*3+1], lgf[s*3+2], sA, sC, Am, G, w);
    float Ae[16], be[4], Ce[10], he[4], Je[10];
    elem_build(Am,G,w,Ae,be,Ce,he,Je);
    if (s==0){
      #pragma unroll
      for (int i=0;i<16;i++) Ar[i]=Ae[i];
      #pragma unroll
      for (int i=0;i<4;i++){ br[i]=be[i]; hr[i]=he[i]; }
      #pragma unroll
      for (int i=0;i<10;i++){ Cr[i]=Ce[i]; Jr[i]=Je[i]; }
    } else {
      compose(Ar,br,Cr,hr,Jr,Ae,be,Ce,he,Je);
    }
    #pragma unroll
    for (int i=0;i<5;i++) av[i]=avn[i];
  }
  float4 buf[11]; float* pb=(float*)buf;
  #pragma unroll
  for (int i=0;i<16;i++) pb[i]=Ar[i];
  #pragma unroll
  for (int i=0;i<4;i++) pb[16+i]=br[i];
  #pragma unroll
  for (int i=0;i<10;i++) pb[20+i]=Cr[i];
  #pragma unroll
  for (int i=0;i<4;i++) pb[30+i]=hr[i];
  #pragma unroll
  for (int i=0;i<10;i++) pb[34+i]=Jr[i];
  #pragma unroll
  for (int p=0;p<11;p++) chel[PIDX(p,c,b)] = buf[p];
}

// ================= Kernel 2: sequential scan over chunk boundaries (filter) =================
__global__ __launch_bounds__(256) void k_fscan(
    const float4* __restrict__ chel, float4* __restrict__ fbound)
{
  int b = blockIdx.x*256+threadIdx.x;
  float m[4]={0.f,0.f,0.f,0.f};
  float S[10]={20.f,0.f,0.f,0.f,20.f,0.f,0.f,20.f,0.f,20.f};
  float4 cur[11], nxt[11];
  #pragma unroll
  for (int p=0;p<11;p++) cur[p]=chel[PIDX(p,0,b)];
  #pragma unroll 1
  for (int c=0;c<NC;c++){
    float4 ob[4]; float* po=(float*)ob;
    #pragma unroll
    for (int i=0;i<4;i++) po[i]=m[i];
    #pragma unroll
    for (int i=0;i<10;i++) po[4+i]=S[i];
    po[14]=0.f; po[15]=0.f;
    #pragma unroll
    for (int p=0;p<4;p++) fbound[PIDX(p,c,b)] = ob[p];
    if (c+1<NC){
      #pragma unroll
      for (int p=0;p<11;p++) nxt[p]=chel[PIDX(p,c+1,b)];
    }
    const float* pe=(const float*)cur;
    elem_apply(pe, pe+16, pe+20, pe+30, pe+34, m, S);
    #pragma unroll
    for (int p=0;p<11;p++) cur[p]=nxt[p];
  }
}

// ================= Kernel 3: filter replay + smoother element emission =================
// el slot layout: slot k (k=0..CL-1) holds E_{c*CL+k}: D[16], e[4], F[10], pad2 (8 float4 planes)
__global__ __launch_bounds__(256) void k_freplay(
    const float* __restrict__ a, const float* __restrict__ logits,
    const float* __restrict__ Abase, const float* __restrict__ Cbase,
    const float4* __restrict__ fbound,
    float4* __restrict__ el, float4* __restrict__ bF0, float4* __restrict__ bL7)
{
  __shared__ float sA[KK*16];
  __shared__ float sC[KK*DA*DZ];
  for (int i=threadIdx.x;i<KK*16;i+=256) sA[i]=Abase[i];
  for (int i=threadIdx.x;i<KK*DA*DZ;i+=256) sC[i]=Cbase[i];
  __syncthreads();
  int tid = blockIdx.x*256+threadIdx.x;
  int b = tid & (BB-1);
  int c = tid >> 11;
  float4 fb[4];
  #pragma unroll
  for (int p=0;p<4;p++) fb[p]=fbound[PIDX(p,c,b)];
  const float* pf=(const float*)fb;
  float z[4]={pf[0],pf[1],pf[2],pf[3]};
  float S[10]={pf[4],pf[5],pf[6],pf[7],pf[8],pf[9],pf[10],pf[11],pf[12],pf[13]};
  const float4* lgp = (const float4*)(logits + ((size_t)b*TT + c*CL)*KK);
  float4 lq0=lgp[0], lq1=lgp[1], lq2=lgp[2];
  float lgf[12]={lq0.x,lq0.y,lq0.z,lq0.w, lq1.x,lq1.y,lq1.z,lq1.w, lq2.x,lq2.y,lq2.z,lq2.w};
  const float4* ap = (const float4*)(a + ((size_t)b*TT + c*CL)*DA);
  float4 av[5], avn[5];
  #pragma unroll
  for (int i=0;i<5;i++) av[i]=ap[i];

  float Mprev[10], pzprev[4];
  #pragma unroll 1
  for (int s=0;s<CL;s++){
    if (s+1<CL){
      #pragma unroll
      for (int i=0;i<5;i++) avn[i]=ap[(s+1)*5+i];
    }
    float Am[16], G[10], w[4];
    mix_from_regs(av, lgf[s*3+0], lgf[s*3+1], lgf[s*3+2], sA, sC, Am, G, w);
    float zh[4];
    mv4(Am,z,zh);
    float Sf[16]; sym_expand(S,Sf);
    float AS[16]; mm4(Am,Sf,AS);
    float P[10];
    {
      int cc=0;
      #pragma unroll
      for (int i=0;i<4;i++){
        #pragma unroll
        for (int j=0;j<4;j++){
          if (j<i) continue;
          float acc = AS[i*4+0]*Am[j*4+0];
          acc = fmaf(AS[i*4+1],Am[j*4+1],acc);
          acc = fmaf(AS[i*4+2],Am[j*4+2],acc);
          acc = fmaf(AS[i*4+3],Am[j*4+3],acc);
          if (i==j) acc += QQ;
          P[cc++] = acc;
        }
      }
    }
    float Pf[16]; sym_expand(P,Pf);
    float Gf[16]; sym_expand(G,Gf);
    float N[16]; mm4(Pf,Gf,N);
    N[0]+=1.f; N[5]+=1.f; N[10]+=1.f; N[15]+=1.f;
    float Ninv[16]; inv4(N,Ninv);
    float Mf[16]; mm4(Ninv,Pf,Mf);
    float M[10]; sym_from_full(Mf,M);
    float u[4];
    #pragma unroll
    for (int i=0;i<4;i++)
      u[i] = w[i] - fmaf(Gf[i*4+3],zh[3],fmaf(Gf[i*4+2],zh[2],fmaf(Gf[i*4+1],zh[1],Gf[i*4+0]*zh[0])));
    float Ms[16]; sym_expand(M,Ms);
    float pz[4];
    #pragma unroll
    for (int i=0;i<4;i++)
      pz[i] = zh[i] + fmaf(Ms[i*4+3],u[3],fmaf(Ms[i*4+2],u[2],fmaf(Ms[i*4+1],u[1],Ms[i*4+0]*u[0])));
    float Pc[10];
    Pc[0]=fmaxf(P[0],1e-4f); Pc[1]=fmaxf(P[1],0.f); Pc[2]=fmaxf(P[2],0.f); Pc[3]=fmaxf(P[3],0.f);
    Pc[4]=fmaxf(P[4],1e-4f); Pc[5]=fmaxf(P[5],0.f); Pc[6]=fmaxf(P[6],0.f);
    Pc[7]=fmaxf(P[7],1e-4f); Pc[8]=fmaxf(P[8],0.f);
    Pc[9]=fmaxf(P[9],1e-4f);

    if (s==0){
      float4 f0[7]; float* p0=(float*)f0;
      #pragma unroll
      for (int i=0;i<16;i++) p0[i]=Am[i];
      #pragma unroll
      for (int i=0;i<10;i++) p0[16+i]=Pc[i];
      p0[26]=0.f; p0[27]=0.f;
      #pragma unroll
      for (int p=0;p<7;p++) bF0[PIDX(p,c,b)] = f0[p];
    } else {
      float D[16], e[4], F[10];
      sm_build(Am, Pc, Mprev, pzprev, D, e, F);
      float4 eb[8]; float* pe2=(float*)eb;
      #pragma unroll
      for (int i=0;i<16;i++) pe2[i]=D[i];
      #pragma unroll
      for (int i=0;i<4;i++) pe2[16+i]=e[i];
      #pragma unroll
      for (int i=0;i<10;i++) pe2[20+i]=F[i];
      pe2[30]=0.f; pe2[31]=0.f;
      int slot = s-1;
      #pragma unroll
      for (int p=0;p<8;p++) el[PIDX(slot*8+p,c,b)] = eb[p];
    }
    #pragma unroll
    for (int i=0;i<10;i++) Mprev[i]=M[i];
    #pragma unroll
    for (int i=0;i<4;i++) pzprev[i]=pz[i];
    #pragma unroll
    for (int i=0;i<4;i++) z[i]=pz[i];
    #pragma unroll
    for (int i=0;i<10;i++) S[i]=M[i];
    #pragma unroll
    for (int i=0;i<5;i++) av[i]=avn[i];
  }
  float4 l7[4]; float* pl=(float*)l7;
  #pragma unroll
  for (int i=0;i<10;i++) pl[i]=Mprev[i];
  #pragma unroll
  for (int i=0;i<4;i++) pl[10+i]=pzprev[i];
  pl[14]=0.f; pl[15]=0.f;
  #pragma unroll
  for (int p=0;p<4;p++) bL7[PIDX(p,c,b)] = l7[p];
}

// ================= Kernel 4: per-chunk smoother composition (+ boundary element) =================
__global__ __launch_bounds__(256) void k_schunk(
    float4* __restrict__ el, const float4* __restrict__ bF0, const float4* __restrict__ bL7,
    float4* __restrict__ smel)
{
  int tid = blockIdx.x*256+threadIdx.x;
  int b = tid & (BB-1);
  int c = tid >> 11;
  float Dr[16], er[4], Fr[10];
  int kstart;
  float4 nxt[8];
  if (c < NC-1){
    // boundary element E_{c*CL+CL-1}: needs (Mlast,pzlast) of chunk c and (A0,Pc0) of chunk c+1
    float4 l7[4];
    #pragma unroll
    for (int p=0;p<4;p++) l7[p]=bL7[PIDX(p,c,b)];
    float4 f0[7];
    #pragma unroll
    for (int p=0;p<7;p++) f0[p]=bF0[PIDX(p,c+1,b)];
    // prefetch slot CL-2 while building boundary
    #pragma unroll
    for (int p=0;p<8;p++) nxt[p]=el[PIDX((CL-2)*8+p,c,b)];
    const float* pl=(const float*)l7;
    float M7[10]={pl[0],pl[1],pl[2],pl[3],pl[4],pl[5],pl[6],pl[7],pl[8],pl[9]};
    float pz7[4]={pl[10],pl[11],pl[12],pl[13]};
    const float* p0=(const float*)f0;
    float A0[16];
    #pragma unroll
    for (int i=0;i<16;i++) A0[i]=p0[i];
    float Pc0[10];
    #pragma unroll
    for (int i=0;i<10;i++) Pc0[i]=p0[16+i];
    sm_build(A0,Pc0,M7,pz7,Dr,er,Fr);
    float4 eb[8]; float* pe2=(float*)eb;
    #pragma unroll
    for (int i=0;i<16;i++) pe2[i]=Dr[i];
    #pragma unroll
    for (int i=0;i<4;i++) pe2[16+i]=er[i];
    #pragma unroll
    for (int i=0;i<10;i++) pe2[20+i]=Fr[i];
    pe2[30]=0.f; pe2[31]=0.f;
    #pragma unroll
    for (int p=0;p<8;p++) el[PIDX((CL-1)*8+p,c,b)] = eb[p];
    kstart = CL-2;
  } else {
    #pragma unroll
    for (int p=0;p<8;p++) nxt[p]=el[PIDX((CL-2)*8+p,c,b)];
    const float* pe=(const float*)nxt;
    #pragma unroll
    for (int i=0;i<16;i++) Dr[i]=pe[i];
    #pragma unroll
    for (int i=0;i<4;i++) er[i]=pe[16+i];
    #pragma unroll
    for (int i=0;i<10;i++) Fr[i]=pe[20+i];
    kstart = CL-3;
    // prefetch slot kstart
    #pragma unroll
    for (int p=0;p<8;p++) nxt[p]=el[PIDX(kstart*8+p,c,b)];
  }
  float4 cur[8];
  if (c < NC-1){
    #pragma unroll
    for (int p=0;p<8;p++) cur[p]=nxt[p];   // slot CL-2
    #pragma unroll
    for (int p=0;p<8;p++) nxt[p]=el[PIDX((CL-3)*8+p,c,b)];
  } else {
    #pragma unroll
    for (int p=0;p<8;p++) cur[p]=nxt[p];   // slot CL-3
    if (CL-4 >= 0){
      #pragma unroll
      for (int p=0;p<8;p++) nxt[p]=el[PIDX((CL-4)*8+p,c,b)];
    }
  }
  #pragma unroll 1
  for (int k=kstart;k>=0;k--){
    const float* pe=(const float*)cur;
    const float* D=pe; const float* e=pe+16; const float* F=pe+20;
    float Dn[16]; mm4(D,Dr,Dn);
    float t1[4]; mv4(D,er,t1);
    #pragma unroll
    for (int i=0;i<4;i++) er[i]=t1[i]+e[i];
    float Ff[16]; sym_expand(Fr,Ff);
    float U[16]; mm4(D,Ff,U);
    float W[16]; mm4_bt(U,D,W);
    float Ws[10]; sym_from_full(W,Ws);
    #pragma unroll
    for (int i=0;i<10;i++) Fr[i]=Ws[i]+F[i];
    #pragma unroll
    for (int i=0;i<16;i++) Dr[i]=Dn[i];
    #pragma unroll
    for (int p=0;p<8;p++) cur[p]=nxt[p];
    if (k-2 >= 0){
      #pragma unroll
      for (int p=0;p<8;p++) nxt[p]=el[PIDX((k-2)*8+p,c,b)];
    }
  }
  float4 ob[8]; float* po=(float*)ob;
  #pragma unroll
  for (int i=0;i<16;i++) po[i]=Dr[i];
  #pragma unroll
  for (int i=0;i<4;i++) po[16+i]=er[i];
  #pragma unroll
  for (int i=0;i<10;i++) po[20+i]=Fr[i];
  po[30]=0.f; po[31]=0.f;
  #pragma unroll
  for (int p=0;p<8;p++) smel[PIDX(p,c,b)] = ob[p];
}

// ================= Kernel 5: backward scan over chunk boundaries (smoother) =================
__global__ __launch_bounds__(256) void k_sscan(
    const float4* __restrict__ smel, const float4* __restrict__ bL7,
    float4* __restrict__ sbound)
{
  int b = blockIdx.x*256+threadIdx.x;
  float4 l7[4];
  #pragma unroll
  for (int p=0;p<4;p++) l7[p]=bL7[PIDX(p,NC-1,b)];
  const float* pl=(const float*)l7;
  float S[10]={pl[0],pl[1],pl[2],pl[3],pl[4],pl[5],pl[6],pl[7],pl[8],pl[9]};
  float z[4]={pl[10],pl[11],pl[12],pl[13]};
  float4 cur[8], nxt[8];
  #pragma unroll
  for (int p=0;p<8;p++) cur[p]=smel[PIDX(p,NC-1,b)];
  #pragma unroll 1
  for (int c=NC-1;c>=0;c--){
    float4 ob[4]; float* po=(float*)ob;
    #pragma unroll
    for (int i=0;i<4;i++) po[i]=z[i];
    #pragma unroll
    for (int i=0;i<10;i++) po[4+i]=S[i];
    po[14]=0.f; po[15]=0.f;
    #pragma unroll
    for (int p=0;p<4;p++) sbound[PIDX(p,c,b)] = ob[p];
    if (c>0){
      #pragma unroll
      for (int p=0;p<8;p++) nxt[p]=smel[PIDX(p,c-1,b)];
    }
    const float* pe=(const float*)cur;
    sm_apply(pe, pe+16, pe+20, z, S);
    #pragma unroll
    for (int p=0;p<8;p++) cur[p]=nxt[p];
  }
}

// ================= Kernel 6: smoother replay within chunks + outputs =================
__global__ __launch_bounds__(256) void k_sreplay(
    const float4* __restrict__ el, const float4* __restrict__ sbound,
    float* __restrict__ out)
{
  int tid = blockIdx.x*256+threadIdx.x;
  int b = tid & (BB-1);
  int c = tid >> 11;
  const size_t Z0 = (size_t)BB*TT*DZ;
  float4 sb[4];
  #pragma unroll
  for (int p=0;p<4;p++) sb[p]=sbound[PIDX(p,c,b)];
  const float* ps=(const float*)sb;
  float z[4]={ps[0],ps[1],ps[2],ps[3]};
  float S[10]={ps[4],ps[5],ps[6],ps[7],ps[8],ps[9],ps[10],ps[11],ps[12],ps[13]};
  int ktop = (c==NC-1) ? (CL-2) : (CL-1);
  float4 cur[8], nxt[8];
  #pragma unroll
  for (int p=0;p<8;p++) cur[p]=el[PIDX(ktop*8+p,c,b)];
  if (c==NC-1){
    *(float4*)(out + ((size_t)b*TT + (TT-1))*DZ) = make_float4(z[0],z[1],z[2],z[3]);
    float Sf[16]; sym_expand(S,Sf);
    float4* so=(float4*)(out + Z0 + ((size_t)b*TT + (TT-1))*16);
    so[0]=make_float4(Sf[0],Sf[1],Sf[2],Sf[3]);
    so[1]=make_float4(Sf[4],Sf[5],Sf[6],Sf[7]);
    so[2]=make_float4(Sf[8],Sf[9],Sf[10],Sf[11]);
    so[3]=make_float4(Sf[12],Sf[13],Sf[14],Sf[15]);
  }
  #pragma unroll 1
  for (int k=ktop;k>=0;k--){
    if (k-1 >= 0){
      #pragma unroll
      for (int p=0;p<8;p++) nxt[p]=el[PIDX((k-1)*8+p,c,b)];
    }
    const float* pe=(const float*)cur;
    sm_apply(pe, pe+16, pe+20, z, S);
    int j = c*CL + k;
    *(float4*)(out + ((size_t)b*TT + j)*DZ) = make_float4(z[0],z[1],z[2],z[3]);
    float Sf[16]; sym_expand(S,Sf);
    float4* so=(float4*)(out + Z0 + ((size_t)b*TT + j)*16);
    so[0]=make_float4(Sf[0],Sf[1],Sf[2],Sf[3]);
    so[1]=make_float4(Sf[4],Sf[5],Sf[6],Sf[7]);
    so[2]=make_float4(Sf[8],Sf[9],Sf[10],Sf[11]);
    so[3]=make_float4(Sf[12],Sf[13],Sf[14],Sf[15]);
    #pragma unroll
    for (int p=0;p<8;p++) cur[p]=nxt[p];
  }
}

extern "C" void kernel_launch(void* const* d_in, const int* in_sizes, int n_in,
                              void* d_out, int out_size, void* d_ws, size_t ws_size,
                              hipStream_t stream) {
  const float* a      = (const float*)d_in[0];
  const float* logits = (const float*)d_in[1];
  const float* Abase  = (const float*)d_in[2];
  const float* Cbase  = (const float*)d_in[3];
  float* out = (float*)d_out;

  float4* ws4 = (float4*)d_ws;
  // el: 32 planes (CL=4 slots x 8). chel aliases el (11 planes; dead before freplay writes el).
  // smel: 8 planes. fbound aliases smel (4 planes; dead before schunk writes smel).
  float4* el     = ws4;
  float4* chel   = el;                          // alias
  float4* smel   = el   + (size_t)(CL*8)*NCH;   // 8 planes
  float4* fbound = smel;                        // alias
  float4* bF0    = smel + (size_t)8*NCH;        // 7 planes
  float4* bL7    = bF0  + (size_t)7*NCH;        // 4 planes
  float4* sbound = bL7  + (size_t)4*NCH;        // 4 planes
  // total = 32+8+7+4+4 = 55 planes * 131072 * 16B = 115.3 MB

  k_fchunk <<<dim3(NCH/256), dim3(256), 0, stream>>>(a, logits, Abase, Cbase, chel);
  k_fscan  <<<dim3(BB/256), dim3(256), 0, stream>>>(chel, fbound);
  k_freplay<<<dim3(NCH/256), dim3(256), 0, stream>>>(a, logits, Abase, Cbase, fbound, el, bF0, bL7);
  k_schunk <<<dim3(NCH/256), dim3(256), 0, stream>>>(el, bF0, bL7, smel);
  k_sscan  <<<dim3(BB/256), dim3(256), 0, stream>>>(smel, bL7, sbound);
  k_sreplay<<<dim3(NCH/256), dim3(256), 0, stream>>>(el, sbound, out);
}

// Round 6
// 253.607 us; speedup vs baseline: 1.4060x; 1.4060x over previous
//
#include <hip/hip_runtime.h>

#define BB 2048
#define TT 256
#define DA 20
#define DZ 4
#define KK 3
#define NC 64      // chunks per sequence (= wave lanes)
#define CL 4       // chunk length (NC*CL == TT)
#define NCH (BB*NC)
#define QQ 0.08f
#define RINV (1.0f/0.03f)

// sym10 layout: [0]=00 [1]=01 [2]=02 [3]=03 [4]=11 [5]=12 [6]=13 [7]=22 [8]=23 [9]=33
__device__ __forceinline__ void sym_expand(const float* s, float* f){
  f[0]=s[0];  f[1]=s[1];  f[2]=s[2];  f[3]=s[3];
  f[4]=s[1];  f[5]=s[4];  f[6]=s[5];  f[7]=s[6];
  f[8]=s[2];  f[9]=s[5];  f[10]=s[7]; f[11]=s[8];
  f[12]=s[3]; f[13]=s[6]; f[14]=s[8]; f[15]=s[9];
}
__device__ __forceinline__ void sym_from_full(const float* F, float* s){
  s[0]=F[0]; s[1]=0.5f*(F[1]+F[4]); s[2]=0.5f*(F[2]+F[8]); s[3]=0.5f*(F[3]+F[12]);
  s[4]=F[5]; s[5]=0.5f*(F[6]+F[9]); s[6]=0.5f*(F[7]+F[13]);
  s[7]=F[10]; s[8]=0.5f*(F[11]+F[14]); s[9]=F[15];
}

__device__ __forceinline__ void inv4(const float* m, float* b){
  float s0 = m[0]*m[5]  - m[4]*m[1];
  float s1 = m[0]*m[6]  - m[4]*m[2];
  float s2 = m[0]*m[7]  - m[4]*m[3];
  float s3 = m[1]*m[6]  - m[5]*m[2];
  float s4 = m[1]*m[7]  - m[5]*m[3];
  float s5 = m[2]*m[7]  - m[6]*m[3];
  float c5 = m[10]*m[15] - m[14]*m[11];
  float c4 = m[9]*m[15]  - m[13]*m[11];
  float c3 = m[9]*m[14]  - m[13]*m[10];
  float c2 = m[8]*m[15]  - m[12]*m[11];
  float c1 = m[8]*m[14]  - m[12]*m[10];
  float c0 = m[8]*m[13]  - m[12]*m[9];
  float det = s0*c5 - s1*c4 + s2*c3 + s3*c2 - s4*c1 + s5*c0;
  float id = 1.0f/det;
  b[0]  = ( m[5]*c5  - m[6]*c4  + m[7]*c3 )*id;
  b[1]  = (-m[1]*c5  + m[2]*c4  - m[3]*c3 )*id;
  b[2]  = ( m[13]*s5 - m[14]*s4 + m[15]*s3)*id;
  b[3]  = (-m[9]*s5  + m[10]*s4 - m[11]*s3)*id;
  b[4]  = (-m[4]*c5  + m[6]*c2  - m[7]*c1 )*id;
  b[5]  = ( m[0]*c5  - m[2]*c2  + m[3]*c1 )*id;
  b[6]  = (-m[12]*s5 + m[14]*s2 - m[15]*s1)*id;
  b[7]  = ( m[8]*s5  - m[10]*s2 + m[11]*s1)*id;
  b[8]  = ( m[4]*c4  - m[5]*c2  + m[7]*c0 )*id;
  b[9]  = (-m[0]*c4  + m[1]*c2  - m[3]*c0 )*id;
  b[10] = ( m[12]*s4 - m[13]*s2 + m[15]*s0)*id;
  b[11] = (-m[8]*s4  + m[9]*s2  - m[11]*s0)*id;
  b[12] = (-m[4]*c3  + m[5]*c1  - m[6]*c0 )*id;
  b[13] = ( m[0]*c3  - m[1]*c1  + m[2]*c0 )*id;
  b[14] = (-m[12]*s3 + m[13]*s1 - m[14]*s0)*id;
  b[15] = ( m[8]*s3  - m[9]*s1  + m[10]*s0)*id;
}

__device__ __forceinline__ void mm4(const float* A, const float* Bm, float* C){
  #pragma unroll
  for (int i=0;i<4;i++){
    #pragma unroll
    for (int j=0;j<4;j++){
      float acc = A[i*4+0]*Bm[0*4+j];
      acc = fmaf(A[i*4+1], Bm[1*4+j], acc);
      acc = fmaf(A[i*4+2], Bm[2*4+j], acc);
      acc = fmaf(A[i*4+3], Bm[3*4+j], acc);
      C[i*4+j] = acc;
    }
  }
}
__device__ __forceinline__ void mm4_bt(const float* A, const float* Bm, float* C){
  #pragma unroll
  for (int i=0;i<4;i++){
    #pragma unroll
    for (int j=0;j<4;j++){
      float acc = A[i*4+0]*Bm[j*4+0];
      acc = fmaf(A[i*4+1], Bm[j*4+1], acc);
      acc = fmaf(A[i*4+2], Bm[j*4+2], acc);
      acc = fmaf(A[i*4+3], Bm[j*4+3], acc);
      C[i*4+j] = acc;
    }
  }
}
__device__ __forceinline__ void mm4_at(const float* A, const float* Bm, float* C){
  #pragma unroll
  for (int i=0;i<4;i++){
    #pragma unroll
    for (int j=0;j<4;j++){
      float acc = A[0*4+i]*Bm[0*4+j];
      acc = fmaf(A[1*4+i], Bm[1*4+j], acc);
      acc = fmaf(A[2*4+i], Bm[2*4+j], acc);
      acc = fmaf(A[3*4+i], Bm[3*4+j], acc);
      C[i*4+j] = acc;
    }
  }
}
__device__ __forceinline__ void mv4(const float* M, const float* v, float* o){
  #pragma unroll
  for (int i=0;i<4;i++)
    o[i] = fmaf(M[i*4+3],v[3],fmaf(M[i*4+2],v[2],fmaf(M[i*4+1],v[1],M[i*4+0]*v[0])));
}
__device__ __forceinline__ void mv4_t(const float* M, const float* v, float* o){
  #pragma unroll
  for (int i=0;i<4;i++)
    o[i] = fmaf(M[12+i],v[3],fmaf(M[8+i],v[2],fmaf(M[4+i],v[1],M[i]*v[0])));
}

// mixing from registers: avq[5] float4 = a[b][t][0..19]
__device__ __forceinline__ void mix_from_regs(
    const float4* avq, float l0, float l1, float l2,
    const float* sA, const float* sC,
    float* Am, float* G, float* w)
{
  float mx = fmaxf(l0, fmaxf(l1,l2));
  float e0=expf(l0-mx), e1=expf(l1-mx), e2=expf(l2-mx);
  float is = 1.0f/(e0+e1+e2);
  float a0=e0*is, a1=e1*is, a2=e2*is;
  #pragma unroll
  for (int c=0;c<16;c++) Am[c] = fmaf(a0,sA[c],fmaf(a1,sA[16+c],a2*sA[32+c]));
  float av[20]={avq[0].x,avq[0].y,avq[0].z,avq[0].w, avq[1].x,avq[1].y,avq[1].z,avq[1].w,
                avq[2].x,avq[2].y,avq[2].z,avq[2].w, avq[3].x,avq[3].y,avq[3].z,avq[3].w,
                avq[4].x,avq[4].y,avq[4].z,avq[4].w};
  #pragma unroll
  for (int c=0;c<10;c++) G[c]=0.f;
  w[0]=0.f;w[1]=0.f;w[2]=0.f;w[3]=0.f;
  #pragma unroll
  for (int d=0; d<DA; d++){
    float ad = av[d];
    float c0 = fmaf(a0, sC[d*4+0], fmaf(a1, sC[80+d*4+0], a2*sC[160+d*4+0]));
    float c1 = fmaf(a0, sC[d*4+1], fmaf(a1, sC[80+d*4+1], a2*sC[160+d*4+1]));
    float c2 = fmaf(a0, sC[d*4+2], fmaf(a1, sC[80+d*4+2], a2*sC[160+d*4+2]));
    float c3 = fmaf(a0, sC[d*4+3], fmaf(a1, sC[80+d*4+3], a2*sC[160+d*4+3]));
    w[0]=fmaf(c0,ad,w[0]); w[1]=fmaf(c1,ad,w[1]); w[2]=fmaf(c2,ad,w[2]); w[3]=fmaf(c3,ad,w[3]);
    G[0]=fmaf(c0,c0,G[0]); G[1]=fmaf(c0,c1,G[1]); G[2]=fmaf(c0,c2,G[2]); G[3]=fmaf(c0,c3,G[3]);
    G[4]=fmaf(c1,c1,G[4]); G[5]=fmaf(c1,c2,G[5]); G[6]=fmaf(c1,c3,G[6]);
    G[7]=fmaf(c2,c2,G[7]); G[8]=fmaf(c2,c3,G[8]);
    G[9]=fmaf(c3,c3,G[9]);
  }
  #pragma unroll
  for (int c=0;c<10;c++) G[c]*=RINV;
  #pragma unroll
  for (int c=0;c<4;c++)  w[c]*=RINV;
}

// filter element: Phi=(I+qG)^-1; A*=Phi A; b*=q Phi w; C*=q Phi; eta*=A^T Phi w; J*=A^T Phi G A
__device__ __forceinline__ void elem_build(const float* Am, const float* G, const float* w,
    float* Ae, float* be, float* Ce, float* he, float* Je)
{
  float Gf[16]; sym_expand(G,Gf);
  float N[16];
  #pragma unroll
  for (int i=0;i<16;i++) N[i] = QQ*Gf[i];
  N[0]+=1.f; N[5]+=1.f; N[10]+=1.f; N[15]+=1.f;
  float Phi[16]; inv4(N,Phi);
  mm4(Phi, Am, Ae);
  float Pw[4]; mv4(Phi, w, Pw);
  #pragma unroll
  for (int i=0;i<4;i++) be[i]=QQ*Pw[i];
  mv4_t(Am, Pw, he);
  float PhiG[16]; mm4(Phi, Gf, PhiG);
  float U[16]; mm4_at(Am, PhiG, U);
  float Jf[16]; mm4(U, Am, Jf);
  sym_from_full(Jf, Je);
  float Cf[16];
  #pragma unroll
  for (int i=0;i<16;i++) Cf[i]=QQ*Phi[i];
  sym_from_full(Cf, Ce);
}

// running(earlier, in-out) = running ⊗ e(later)
__device__ __forceinline__ void compose(float* Ar, float* br, float* Cr, float* hr, float* Jr,
    const float* Ae, const float* be, const float* Ce, const float* he, const float* Je)
{
  float Crf[16]; sym_expand(Cr,Crf);
  float Jef[16]; sym_expand(Je,Jef);
  float N[16]; mm4(Crf,Jef,N);
  N[0]+=1.f; N[5]+=1.f; N[10]+=1.f; N[15]+=1.f;
  float E[16]; inv4(N,E);
  float EA[16]; mm4(E,Ar,EA);
  float Anew[16]; mm4(Ae,EA,Anew);
  float t1[4]; mv4(Crf,he,t1);
  #pragma unroll
  for (int i=0;i<4;i++) t1[i]+=br[i];
  float t2[4]; mv4(E,t1,t2);
  float bnew[4]; mv4(Ae,t2,bnew);
  #pragma unroll
  for (int i=0;i<4;i++) bnew[i]+=be[i];
  float EC[16]; mm4(E,Crf,EC);
  float AEC[16]; mm4(Ae,EC,AEC);
  float Cfull[16]; mm4_bt(AEC,Ae,Cfull);
  float Cnew[10]; sym_from_full(Cfull,Cnew);
  #pragma unroll
  for (int i=0;i<10;i++) Cnew[i]+=Ce[i];
  float v[4]; mv4(Jef,br,v);
  #pragma unroll
  for (int i=0;i<4;i++) v[i]=he[i]-v[i];
  float Ev[4]; mv4_t(E,v,Ev);
  float hnew[4]; mv4_t(Ar,Ev,hnew);
  #pragma unroll
  for (int i=0;i<4;i++) hnew[i]+=hr[i];
  float EtJ[16]; mm4_at(E,Jef,EtJ);
  float AtEtJ[16]; mm4_at(Ar,EtJ,AtEtJ);
  float Jfull[16]; mm4(AtEtJ,Ar,Jfull);
  float Jnew[10]; sym_from_full(Jfull,Jnew);
  #pragma unroll
  for (int i=0;i<10;i++) Jnew[i]+=Jr[i];
  #pragma unroll
  for (int i=0;i<16;i++) Ar[i]=Anew[i];
  #pragma unroll
  for (int i=0;i<4;i++){ br[i]=bnew[i]; hr[i]=hnew[i]; }
  #pragma unroll
  for (int i=0;i<10;i++){ Cr[i]=Cnew[i]; Jr[i]=Jnew[i]; }
}

// apply filter element to state (m,S)
__device__ __forceinline__ void elem_apply(const float* Ae, const float* be, const float* Ce,
    const float* he, const float* Je, float* m, float* S)
{
  float Pf[16]; sym_expand(S,Pf);
  float Jf[16]; sym_expand(Je,Jf);
  float N[16]; mm4(Pf,Jf,N);
  N[0]+=1.f; N[5]+=1.f; N[10]+=1.f; N[15]+=1.f;
  float T[16]; inv4(N,T);
  float t1[4]; mv4(Pf,he,t1);
  #pragma unroll
  for (int i=0;i<4;i++) t1[i]+=m[i];
  float t2[4]; mv4(T,t1,t2);
  float mn[4]; mv4(Ae,t2,mn);
  #pragma unroll
  for (int i=0;i<4;i++) mn[i]+=be[i];
  float TP[16]; mm4(T,Pf,TP);
  float ATP[16]; mm4(Ae,TP,ATP);
  float Pn[16]; mm4_bt(ATP,Ae,Pn);
  float Sn[10]; sym_from_full(Pn,Sn);
  #pragma unroll
  for (int i=0;i<10;i++) S[i]=Sn[i]+Ce[i];
  #pragma unroll
  for (int i=0;i<4;i++) m[i]=mn[i];
}

// smoother element: D = Mj A1^T inv(Pc1); e = pzj - D (A1 pzj); F = Mj - D Pc1 D^T
__device__ __forceinline__ void sm_build(const float* A1, const float* Pc1,
    const float* Mj, const float* pzj, float* D, float* e, float* F)
{
  float Pcf[16]; sym_expand(Pc1,Pcf);
  float E[16]; inv4(Pcf,E);
  float Mf[16]; sym_expand(Mj,Mf);
  float MB[16]; mm4_bt(Mf,A1,MB);
  mm4(MB,E,D);
  float zh[4]; mv4(A1,pzj,zh);
  float Dzh[4]; mv4(D,zh,Dzh);
  #pragma unroll
  for (int i=0;i<4;i++) e[i]=pzj[i]-Dzh[i];
  float U[16]; mm4(D,Pcf,U);
  float W[16]; mm4_bt(U,D,W);
  float Ws[10]; sym_from_full(W,Ws);
  #pragma unroll
  for (int i=0;i<10;i++) F[i]=Mj[i]-Ws[i];
}

// apply smoother element: z' = D z + e; S' = D S D^T + F
__device__ __forceinline__ void sm_apply(const float* D, const float* e, const float* F,
    float* z, float* S)
{
  float zn[4]; mv4(D,z,zn);
  #pragma unroll
  for (int i=0;i<4;i++) z[i]=zn[i]+e[i];
  float Sf[16]; sym_expand(S,Sf);
  float U[16]; mm4(D,Sf,U);
  float W[16]; mm4_bt(U,D,W);
  float Sn[10]; sym_from_full(W,Sn);
  #pragma unroll
  for (int i=0;i<10;i++) S[i]=Sn[i]+F[i];
}

// affine pre-compose: running = Ek ∘ running  (Ek applied after running)
__device__ __forceinline__ void aff_pre(float* Dr, float* er, float* Fr,
    const float* Dk, const float* ek, const float* Fk)
{
  float Dn[16]; mm4(Dk,Dr,Dn);
  float t1[4]; mv4(Dk,er,t1);
  float Frf[16]; sym_expand(Fr,Frf);
  float U[16]; mm4(Dk,Frf,U);
  float W[16]; mm4_bt(U,Dk,W);
  float Ws[10]; sym_from_full(W,Ws);
  #pragma unroll
  for (int i=0;i<4;i++) er[i]=t1[i]+ek[i];
  #pragma unroll
  for (int i=0;i<10;i++) Fr[i]=Ws[i]+Fk[i];
  #pragma unroll
  for (int i=0;i<16;i++) Dr[i]=Dn[i];
}

// ===== Kernel 1: fused per-chunk filter element + wave-parallel prefix scan =====
// lane = chunk c, wave = batch b. Writes fbound[b][c] = state (m,S) at chunk start.
__global__ __launch_bounds__(256) void k_fwd(
    const float* __restrict__ a, const float* __restrict__ logits,
    const float* __restrict__ Abase, const float* __restrict__ Cbase,
    float4* __restrict__ fbound)
{
  __shared__ float sA[KK*16];
  __shared__ float sC[KK*DA*DZ];
  for (int i=threadIdx.x;i<KK*16;i+=256) sA[i]=Abase[i];
  for (int i=threadIdx.x;i<KK*DA*DZ;i+=256) sC[i]=Cbase[i];
  __syncthreads();
  int lane = threadIdx.x & 63;
  int b = blockIdx.x*4 + (threadIdx.x>>6);
  int c = lane;

  const float4* lgp = (const float4*)(logits + ((size_t)b*TT + c*CL)*KK);
  float4 lq0=lgp[0], lq1=lgp[1], lq2=lgp[2];
  float lgf[12]={lq0.x,lq0.y,lq0.z,lq0.w, lq1.x,lq1.y,lq1.z,lq1.w, lq2.x,lq2.y,lq2.z,lq2.w};
  const float4* ap = (const float4*)(a + ((size_t)b*TT + c*CL)*DA);

  // X = packed chunk composite: A[0:16], b[16:20], C[20:30], h[30:34], J[34:44]
  float X[44];
  #pragma unroll 1
  for (int s=0;s<CL;s++){
    float4 av[5];
    #pragma unroll
    for (int i=0;i<5;i++) av[i]=ap[s*5+i];
    float Am[16], G[10], w[4];
    mix_from_regs(av, lgf[s*3+0], lgf[s*3+1], lgf[s*3+2], sA, sC, Am, G, w);
    float Ae[16], be[4], Ce[10], he[4], Je[10];
    elem_build(Am,G,w,Ae,be,Ce,he,Je);
    if (s==0){
      #pragma unroll
      for (int i=0;i<16;i++) X[i]=Ae[i];
      #pragma unroll
      for (int i=0;i<4;i++){ X[16+i]=be[i]; X[30+i]=he[i]; }
      #pragma unroll
      for (int i=0;i<10;i++){ X[20+i]=Ce[i]; X[34+i]=Je[i]; }
    } else {
      compose(X, X+16, X+20, X+30, X+34, Ae, be, Ce, he, Je);
    }
  }

  // Kogge-Stone inclusive prefix scan over lanes (non-commutative)
  #pragma unroll 1
  for (int d=1; d<NC; d<<=1){
    float P[44];
    #pragma unroll
    for (int i=0;i<44;i++) P[i] = __shfl_up(X[i], d, 64);
    if (lane >= d){
      compose(P, P+16, P+20, P+30, P+34, X, X+16, X+20, X+30, X+34);
      #pragma unroll
      for (int i=0;i<44;i++) X[i]=P[i];
    }
  }

  // exclusive shift + apply to initial state (0, 20 I)
  float Pm[44];
  #pragma unroll
  for (int i=0;i<44;i++) Pm[i] = __shfl_up(X[i], 1, 64);
  float m[4]={0.f,0.f,0.f,0.f};
  float S[10]={20.f,0.f,0.f,0.f,20.f,0.f,0.f,20.f,0.f,20.f};
  if (lane > 0) elem_apply(Pm, Pm+16, Pm+20, Pm+30, Pm+34, m, S);

  float4 ob[4]; float* po=(float*)ob;
  #pragma unroll
  for (int i=0;i<4;i++) po[i]=m[i];
  #pragma unroll
  for (int i=0;i<10;i++) po[4+i]=S[i];
  po[14]=0.f; po[15]=0.f;
  float4* dst = fbound + ((size_t)b*NC + c)*4;
  #pragma unroll
  for (int p=0;p<4;p++) dst[p]=ob[p];
}

// ===== Kernel 2: filter replay + smoother element emission (b-fast, coalesced) =====
// el[b][c][slot][8 f4]: slot k holds E_{c*CL+k} = D[16],e[4],F[10],pad2
__global__ __launch_bounds__(256) void k_freplay(
    const float* __restrict__ a, const float* __restrict__ logits,
    const float* __restrict__ Abase, const float* __restrict__ Cbase,
    const float4* __restrict__ fbound,
    float4* __restrict__ el, float4* __restrict__ bF0, float4* __restrict__ bL7)
{
  __shared__ float sA[KK*16];
  __shared__ float sC[KK*DA*DZ];
  for (int i=threadIdx.x;i<KK*16;i+=256) sA[i]=Abase[i];
  for (int i=threadIdx.x;i<KK*DA*DZ;i+=256) sC[i]=Cbase[i];
  __syncthreads();
  int tid = blockIdx.x*256+threadIdx.x;
  int b = tid & (BB-1);
  int c = tid >> 11;
  float4 fb[4];
  const float4* fsrc = fbound + ((size_t)b*NC + c)*4;
  #pragma unroll
  for (int p=0;p<4;p++) fb[p]=fsrc[p];
  const float* pf=(const float*)fb;
  float z[4]={pf[0],pf[1],pf[2],pf[3]};
  float S[10]={pf[4],pf[5],pf[6],pf[7],pf[8],pf[9],pf[10],pf[11],pf[12],pf[13]};
  const float4* lgp = (const float4*)(logits + ((size_t)b*TT + c*CL)*KK);
  float4 lq0=lgp[0], lq1=lgp[1], lq2=lgp[2];
  float lgf[12]={lq0.x,lq0.y,lq0.z,lq0.w, lq1.x,lq1.y,lq1.z,lq1.w, lq2.x,lq2.y,lq2.z,lq2.w};
  const float4* ap = (const float4*)(a + ((size_t)b*TT + c*CL)*DA);
  float4 av[5], avn[5];
  #pragma unroll
  for (int i=0;i<5;i++) av[i]=ap[i];

  float Mprev[10], pzprev[4];
  #pragma unroll 1
  for (int s=0;s<CL;s++){
    if (s+1<CL){
      #pragma unroll
      for (int i=0;i<5;i++) avn[i]=ap[(s+1)*5+i];
    }
    float Am[16], G[10], w[4];
    mix_from_regs(av, lgf[s*3+0], lgf[s*3+1], lgf[s*3+2], sA, sC, Am, G, w);
    float zh[4];
    mv4(Am,z,zh);
    float Sf[16]; sym_expand(S,Sf);
    float AS[16]; mm4(Am,Sf,AS);
    float P[10];
    {
      int cc=0;
      #pragma unroll
      for (int i=0;i<4;i++){
        #pragma unroll
        for (int j=0;j<4;j++){
          if (j<i) continue;
          float acc = AS[i*4+0]*Am[j*4+0];
          acc = fmaf(AS[i*4+1],Am[j*4+1],acc);
          acc = fmaf(AS[i*4+2],Am[j*4+2],acc);
          acc = fmaf(AS[i*4+3],Am[j*4+3],acc);
          if (i==j) acc += QQ;
          P[cc++] = acc;
        }
      }
    }
    float Pf[16]; sym_expand(P,Pf);
    float Gf[16]; sym_expand(G,Gf);
    float N[16]; mm4(Pf,Gf,N);
    N[0]+=1.f; N[5]+=1.f; N[10]+=1.f; N[15]+=1.f;
    float Ninv[16]; inv4(N,Ninv);
    float Mf[16]; mm4(Ninv,Pf,Mf);
    float M[10]; sym_from_full(Mf,M);
    float u[4];
    #pragma unroll
    for (int i=0;i<4;i++)
      u[i] = w[i] - fmaf(Gf[i*4+3],zh[3],fmaf(Gf[i*4+2],zh[2],fmaf(Gf[i*4+1],zh[1],Gf[i*4+0]*zh[0])));
    float Ms[16]; sym_expand(M,Ms);
    float pz[4];
    #pragma unroll
    for (int i=0;i<4;i++)
      pz[i] = zh[i] + fmaf(Ms[i*4+3],u[3],fmaf(Ms[i*4+2],u[2],fmaf(Ms[i*4+1],u[1],Ms[i*4+0]*u[0])));
    float Pc[10];
    Pc[0]=fmaxf(P[0],1e-4f); Pc[1]=fmaxf(P[1],0.f); Pc[2]=fmaxf(P[2],0.f); Pc[3]=fmaxf(P[3],0.f);
    Pc[4]=fmaxf(P[4],1e-4f); Pc[5]=fmaxf(P[5],0.f); Pc[6]=fmaxf(P[6],0.f);
    Pc[7]=fmaxf(P[7],1e-4f); Pc[8]=fmaxf(P[8],0.f);
    Pc[9]=fmaxf(P[9],1e-4f);

    if (s==0){
      float4 f0[7]; float* p0=(float*)f0;
      #pragma unroll
      for (int i=0;i<16;i++) p0[i]=Am[i];
      #pragma unroll
      for (int i=0;i<10;i++) p0[16+i]=Pc[i];
      p0[26]=0.f; p0[27]=0.f;
      float4* d0 = bF0 + ((size_t)b*NC + c)*7;
      #pragma unroll
      for (int p=0;p<7;p++) d0[p]=f0[p];
    } else {
      float D[16], e[4], F[10];
      sm_build(Am, Pc, Mprev, pzprev, D, e, F);
      float4 eb[8]; float* pe2=(float*)eb;
      #pragma unroll
      for (int i=0;i<16;i++) pe2[i]=D[i];
      #pragma unroll
      for (int i=0;i<4;i++) pe2[16+i]=e[i];
      #pragma unroll
      for (int i=0;i<10;i++) pe2[20+i]=F[i];
      pe2[30]=0.f; pe2[31]=0.f;
      float4* de = el + (((size_t)b*NC + c)*CL + (s-1))*8;
      #pragma unroll
      for (int p=0;p<8;p++) de[p]=eb[p];
    }
    #pragma unroll
    for (int i=0;i<10;i++) Mprev[i]=M[i];
    #pragma unroll
    for (int i=0;i<4;i++) pzprev[i]=pz[i];
    #pragma unroll
    for (int i=0;i<4;i++) z[i]=pz[i];
    #pragma unroll
    for (int i=0;i<10;i++) S[i]=M[i];
    #pragma unroll
    for (int i=0;i<5;i++) av[i]=avn[i];
  }
  float4 l7[4]; float* pl=(float*)l7;
  #pragma unroll
  for (int i=0;i<10;i++) pl[i]=Mprev[i];
  #pragma unroll
  for (int i=0;i<4;i++) pl[10+i]=pzprev[i];
  pl[14]=0.f; pl[15]=0.f;
  float4* dl = bL7 + ((size_t)b*NC + c)*4;
  #pragma unroll
  for (int p=0;p<4;p++) dl[p]=l7[p];
}

// ===== Kernel 3: fused per-chunk smoother composite + wave-parallel suffix scan =====
// lane = chunk c. Writes sbound[b][c] = smoothed state at chunk c's top boundary,
// and el slot CL-1 (the chunk-boundary smoother element) for c < NC-1.
__global__ __launch_bounds__(256) void k_bwd(
    float4* __restrict__ el, const float4* __restrict__ bF0, const float4* __restrict__ bL7,
    float4* __restrict__ sbound)
{
  int lane = threadIdx.x & 63;
  int b = blockIdx.x*4 + (threadIdx.x>>6);
  int c = lane;

  // Y = packed affine composite: D[0:16], e[16:20], F[20:30]
  float Y[30];
  int kstart;
  if (c < NC-1){
    float4 l7[4];
    const float4* sl = bL7 + ((size_t)b*NC + c)*4;
    #pragma unroll
    for (int p=0;p<4;p++) l7[p]=sl[p];
    float4 f0[7];
    const float4* s0 = bF0 + ((size_t)b*NC + (c+1))*7;
    #pragma unroll
    for (int p=0;p<7;p++) f0[p]=s0[p];
    const float* pl=(const float*)l7;
    const float* p0=(const float*)f0;
    float M7[10]={pl[0],pl[1],pl[2],pl[3],pl[4],pl[5],pl[6],pl[7],pl[8],pl[9]};
    float pz7[4]={pl[10],pl[11],pl[12],pl[13]};
    float A0[16];
    #pragma unroll
    for (int i=0;i<16;i++) A0[i]=p0[i];
    float Pc0[10];
    #pragma unroll
    for (int i=0;i<10;i++) Pc0[i]=p0[16+i];
    sm_build(A0,Pc0,M7,pz7, Y, Y+16, Y+20);
    // store boundary element as el slot CL-1 (k_sreplay applies it)
    float4 eb[8]; float* pe2=(float*)eb;
    #pragma unroll
    for (int i=0;i<16;i++) pe2[i]=Y[i];
    #pragma unroll
    for (int i=0;i<4;i++) pe2[16+i]=Y[16+i];
    #pragma unroll
    for (int i=0;i<10;i++) pe2[20+i]=Y[20+i];
    pe2[30]=0.f; pe2[31]=0.f;
    float4* de = el + (((size_t)b*NC + c)*CL + (CL-1))*8;
    #pragma unroll
    for (int p=0;p<8;p++) de[p]=eb[p];
    kstart = CL-2;
  } else {
    float4 eb[8];
    const float4* se = el + (((size_t)b*NC + c)*CL + (CL-2))*8;
    #pragma unroll
    for (int p=0;p<8;p++) eb[p]=se[p];
    const float* pe=(const float*)eb;
    #pragma unroll
    for (int i=0;i<30;i++) Y[i]=pe[i];
    kstart = CL-3;
  }
  #pragma unroll 1
  for (int k=kstart;k>=0;k--){
    float4 eb[8];
    const float4* se = el + (((size_t)b*NC + c)*CL + k)*8;
    #pragma unroll
    for (int p=0;p<8;p++) eb[p]=se[p];
    const float* pe=(const float*)eb;
    aff_pre(Y, Y+16, Y+20, pe, pe+16, pe+20);
  }

  // Kogge-Stone suffix scan: own = own ∘ partner(from lane c+d), partner applied first
  #pragma unroll 1
  for (int d=1; d<NC; d<<=1){
    float P[30];
    #pragma unroll
    for (int i=0;i<30;i++) P[i] = __shfl_down(Y[i], d, 64);
    if (c + d < NC){
      aff_pre(P, P+16, P+20, Y, Y+16, Y+20);   // P(result) = Y(own,after) ∘ P(partner,first)
      #pragma unroll
      for (int i=0;i<30;i++) Y[i]=P[i];
    }
  }

  // terminal smoothed state = filter posterior at t=TT-1 (bL7 of chunk NC-1)
  const float4* tl = bL7 + ((size_t)b*NC + (NC-1))*4;
  float4 t0=tl[0],t1q=tl[1],t2q=tl[2],t3q=tl[3];
  const float* pt=(const float*)&t0;
  float S[10]={t0.x,t0.y,t0.z,t0.w, t1q.x,t1q.y,t1q.z,t1q.w, t2q.x,t2q.y};
  float z[4]={t2q.z,t2q.w,t3q.x,t3q.y};
  (void)pt;

  // sbound_c = H'_{c+1} applied to terminal (lane NC-1: terminal itself)
  float Pn[30];
  #pragma unroll
  for (int i=0;i<30;i++) Pn[i] = __shfl_down(Y[i], 1, 64);
  if (c < NC-1) sm_apply(Pn, Pn+16, Pn+20, z, S);

  float4 ob[4]; float* po=(float*)ob;
  #pragma unroll
  for (int i=0;i<4;i++) po[i]=z[i];
  #pragma unroll
  for (int i=0;i<10;i++) po[4+i]=S[i];
  po[14]=0.f; po[15]=0.f;
  float4* dst = sbound + ((size_t)b*NC + c)*4;
  #pragma unroll
  for (int p=0;p<4;p++) dst[p]=ob[p];
}

// ===== Kernel 4: smoother replay within chunks + outputs (b-fast) =====
__global__ __launch_bounds__(256) void k_sreplay(
    const float4* __restrict__ el, const float4* __restrict__ sbound,
    float* __restrict__ out)
{
  int tid = blockIdx.x*256+threadIdx.x;
  int b = tid & (BB-1);
  int c = tid >> 11;
  const size_t Z0 = (size_t)BB*TT*DZ;
  float4 sb[4];
  const float4* ssrc = sbound + ((size_t)b*NC + c)*4;
  #pragma unroll
  for (int p=0;p<4;p++) sb[p]=ssrc[p];
  const float* ps=(const float*)sb;
  float z[4]={ps[0],ps[1],ps[2],ps[3]};
  float S[10]={ps[4],ps[5],ps[6],ps[7],ps[8],ps[9],ps[10],ps[11],ps[12],ps[13]};
  int ktop = (c==NC-1) ? (CL-2) : (CL-1);
  float4 cur[8], nxt[8];
  const float4* base = el + ((size_t)b*NC + c)*CL*8;
  #pragma unroll
  for (int p=0;p<8;p++) cur[p]=base[ktop*8+p];
  if (c==NC-1){
    *(float4*)(out + ((size_t)b*TT + (TT-1))*DZ) = make_float4(z[0],z[1],z[2],z[3]);
    float Sf[16]; sym_expand(S,Sf);
    float4* so=(float4*)(out + Z0 + ((size_t)b*TT + (TT-1))*16);
    so[0]=make_float4(Sf[0],Sf[1],Sf[2],Sf[3]);
    so[1]=make_float4(Sf[4],Sf[5],Sf[6],Sf[7]);
    so[2]=make_float4(Sf[8],Sf[9],Sf[10],Sf[11]);
    so[3]=make_float4(Sf[12],Sf[13],Sf[14],Sf[15]);
  }
  #pragma unroll 1
  for (int k=ktop;k>=0;k--){
    if (k-1 >= 0){
      #pragma unroll
      for (int p=0;p<8;p++) nxt[p]=base[(k-1)*8+p];
    }
    const float* pe=(const float*)cur;
    sm_apply(pe, pe+16, pe+20, z, S);
    int j = c*CL + k;
    *(float4*)(out + ((size_t)b*TT + j)*DZ) = make_float4(z[0],z[1],z[2],z[3]);
    float Sf[16]; sym_expand(S,Sf);
    float4* so=(float4*)(out + Z0 + ((size_t)b*TT + j)*16);
    so[0]=make_float4(Sf[0],Sf[1],Sf[2],Sf[3]);
    so[1]=make_float4(Sf[4],Sf[5],Sf[6],Sf[7]);
    so[2]=make_float4(Sf[8],Sf[9],Sf[10],Sf[11]);
    so[3]=make_float4(Sf[12],Sf[13],Sf[14],Sf[15]);
    #pragma unroll
    for (int p=0;p<8;p++) cur[p]=nxt[p];
  }
}

extern "C" void kernel_launch(void* const* d_in, const int* in_sizes, int n_in,
                              void* d_out, int out_size, void* d_ws, size_t ws_size,
                              hipStream_t stream) {
  const float* a      = (const float*)d_in[0];
  const float* logits = (const float*)d_in[1];
  const float* Abase  = (const float*)d_in[2];
  const float* Cbase  = (const float*)d_in[3];
  float* out = (float*)d_out;

  float4* ws4 = (float4*)d_ws;
  // AoS blobs per (b,c): fbound 4 f4 | el 32 f4 (4 slots x 8) | bF0 7 f4 | bL7 4 f4 | sbound 4 f4
  float4* fbound = ws4;                           // 4  * NCH
  float4* el     = fbound + (size_t)4*NCH;        // 32 * NCH
  float4* bF0    = el     + (size_t)32*NCH;       // 7  * NCH
  float4* bL7    = bF0    + (size_t)7*NCH;        // 4  * NCH
  float4* sbound = bL7    + (size_t)4*NCH;        // 4  * NCH  (51 f4 * 131072 = 107 MB)

  k_fwd    <<<dim3(BB/4),   dim3(256), 0, stream>>>(a, logits, Abase, Cbase, fbound);
  k_freplay<<<dim3(NCH/256),dim3(256), 0, stream>>>(a, logits, Abase, Cbase, fbound, el, bF0, bL7);
  k_bwd    <<<dim3(BB/4),   dim3(256), 0, stream>>>(el, bF0, bL7, sbound);
  k_sreplay<<<dim3(NCH/256),dim3(256), 0, stream>>>(el, sbound, out);
}

// Round 7
// 215.756 us; speedup vs baseline: 1.6527x; 1.1754x over previous
//
#include <hip/hip_runtime.h>

#define BB 2048
#define TT 256
#define DA 20
#define DZ 4
#define KK 3
#define NC 64      // chunks per sequence (= wave lanes)
#define CL 4       // chunk length (NC*CL == TT)
#define NCH (BB*NC)
#define QQ 0.08f
#define RINV (1.0f/0.03f)

// sym10 layout: [0]=00 [1]=01 [2]=02 [3]=03 [4]=11 [5]=12 [6]=13 [7]=22 [8]=23 [9]=33
__device__ __forceinline__ void sym_expand(const float* s, float* f){
  f[0]=s[0];  f[1]=s[1];  f[2]=s[2];  f[3]=s[3];
  f[4]=s[1];  f[5]=s[4];  f[6]=s[5];  f[7]=s[6];
  f[8]=s[2];  f[9]=s[5];  f[10]=s[7]; f[11]=s[8];
  f[12]=s[3]; f[13]=s[6]; f[14]=s[8]; f[15]=s[9];
}
__device__ __forceinline__ void sym_from_full(const float* F, float* s){
  s[0]=F[0]; s[1]=0.5f*(F[1]+F[4]); s[2]=0.5f*(F[2]+F[8]); s[3]=0.5f*(F[3]+F[12]);
  s[4]=F[5]; s[5]=0.5f*(F[6]+F[9]); s[6]=0.5f*(F[7]+F[13]);
  s[7]=F[10]; s[8]=0.5f*(F[11]+F[14]); s[9]=F[15];
}

__device__ __forceinline__ void inv4(const float* m, float* b){
  float s0 = m[0]*m[5]  - m[4]*m[1];
  float s1 = m[0]*m[6]  - m[4]*m[2];
  float s2 = m[0]*m[7]  - m[4]*m[3];
  float s3 = m[1]*m[6]  - m[5]*m[2];
  float s4 = m[1]*m[7]  - m[5]*m[3];
  float s5 = m[2]*m[7]  - m[6]*m[3];
  float c5 = m[10]*m[15] - m[14]*m[11];
  float c4 = m[9]*m[15]  - m[13]*m[11];
  float c3 = m[9]*m[14]  - m[13]*m[10];
  float c2 = m[8]*m[15]  - m[12]*m[11];
  float c1 = m[8]*m[14]  - m[12]*m[10];
  float c0 = m[8]*m[13]  - m[12]*m[9];
  float det = s0*c5 - s1*c4 + s2*c3 + s3*c2 - s4*c1 + s5*c0;
  float id = 1.0f/det;
  b[0]  = ( m[5]*c5  - m[6]*c4  + m[7]*c3 )*id;
  b[1]  = (-m[1]*c5  + m[2]*c4  - m[3]*c3 )*id;
  b[2]  = ( m[13]*s5 - m[14]*s4 + m[15]*s3)*id;
  b[3]  = (-m[9]*s5  + m[10]*s4 - m[11]*s3)*id;
  b[4]  = (-m[4]*c5  + m[6]*c2  - m[7]*c1 )*id;
  b[5]  = ( m[0]*c5  - m[2]*c2  + m[3]*c1 )*id;
  b[6]  = (-m[12]*s5 + m[14]*s2 - m[15]*s1)*id;
  b[7]  = ( m[8]*s5  - m[10]*s2 + m[11]*s1)*id;
  b[8]  = ( m[4]*c4  - m[5]*c2  + m[7]*c0 )*id;
  b[9]  = (-m[0]*c4  + m[1]*c2  - m[3]*c0 )*id;
  b[10] = ( m[12]*s4 - m[13]*s2 + m[15]*s0)*id;
  b[11] = (-m[8]*s4  + m[9]*s2  - m[11]*s0)*id;
  b[12] = (-m[4]*c3  + m[5]*c1  - m[6]*c0 )*id;
  b[13] = ( m[0]*c3  - m[1]*c1  + m[2]*c0 )*id;
  b[14] = (-m[12]*s3 + m[13]*s1 - m[14]*s0)*id;
  b[15] = ( m[8]*s3  - m[9]*s1  + m[10]*s0)*id;
}

__device__ __forceinline__ void mm4(const float* A, const float* Bm, float* C){
  #pragma unroll
  for (int i=0;i<4;i++){
    #pragma unroll
    for (int j=0;j<4;j++){
      float acc = A[i*4+0]*Bm[0*4+j];
      acc = fmaf(A[i*4+1], Bm[1*4+j], acc);
      acc = fmaf(A[i*4+2], Bm[2*4+j], acc);
      acc = fmaf(A[i*4+3], Bm[3*4+j], acc);
      C[i*4+j] = acc;
    }
  }
}
__device__ __forceinline__ void mm4_bt(const float* A, const float* Bm, float* C){
  #pragma unroll
  for (int i=0;i<4;i++){
    #pragma unroll
    for (int j=0;j<4;j++){
      float acc = A[i*4+0]*Bm[j*4+0];
      acc = fmaf(A[i*4+1], Bm[j*4+1], acc);
      acc = fmaf(A[i*4+2], Bm[j*4+2], acc);
      acc = fmaf(A[i*4+3], Bm[j*4+3], acc);
      C[i*4+j] = acc;
    }
  }
}
__device__ __forceinline__ void mm4_at(const float* A, const float* Bm, float* C){
  #pragma unroll
  for (int i=0;i<4;i++){
    #pragma unroll
    for (int j=0;j<4;j++){
      float acc = A[0*4+i]*Bm[0*4+j];
      acc = fmaf(A[1*4+i], Bm[1*4+j], acc);
      acc = fmaf(A[2*4+i], Bm[2*4+j], acc);
      acc = fmaf(A[3*4+i], Bm[3*4+j], acc);
      C[i*4+j] = acc;
    }
  }
}
__device__ __forceinline__ void mv4(const float* M, const float* v, float* o){
  #pragma unroll
  for (int i=0;i<4;i++)
    o[i] = fmaf(M[i*4+3],v[3],fmaf(M[i*4+2],v[2],fmaf(M[i*4+1],v[1],M[i*4+0]*v[0])));
}
__device__ __forceinline__ void mv4_t(const float* M, const float* v, float* o){
  #pragma unroll
  for (int i=0;i<4;i++)
    o[i] = fmaf(M[12+i],v[3],fmaf(M[8+i],v[2],fmaf(M[4+i],v[1],M[i]*v[0])));
}

// mixing from registers: avq[5] float4 = a[b][t][0..19]
__device__ __forceinline__ void mix_from_regs(
    const float4* avq, float l0, float l1, float l2,
    const float* sA, const float* sC,
    float* Am, float* G, float* w)
{
  float mx = fmaxf(l0, fmaxf(l1,l2));
  float e0=expf(l0-mx), e1=expf(l1-mx), e2=expf(l2-mx);
  float is = 1.0f/(e0+e1+e2);
  float a0=e0*is, a1=e1*is, a2=e2*is;
  #pragma unroll
  for (int c=0;c<16;c++) Am[c] = fmaf(a0,sA[c],fmaf(a1,sA[16+c],a2*sA[32+c]));
  float av[20]={avq[0].x,avq[0].y,avq[0].z,avq[0].w, avq[1].x,avq[1].y,avq[1].z,avq[1].w,
                avq[2].x,avq[2].y,avq[2].z,avq[2].w, avq[3].x,avq[3].y,avq[3].z,avq[3].w,
                avq[4].x,avq[4].y,avq[4].z,avq[4].w};
  #pragma unroll
  for (int c=0;c<10;c++) G[c]=0.f;
  w[0]=0.f;w[1]=0.f;w[2]=0.f;w[3]=0.f;
  #pragma unroll
  for (int d=0; d<DA; d++){
    float ad = av[d];
    float c0 = fmaf(a0, sC[d*4+0], fmaf(a1, sC[80+d*4+0], a2*sC[160+d*4+0]));
    float c1 = fmaf(a0, sC[d*4+1], fmaf(a1, sC[80+d*4+1], a2*sC[160+d*4+1]));
    float c2 = fmaf(a0, sC[d*4+2], fmaf(a1, sC[80+d*4+2], a2*sC[160+d*4+2]));
    float c3 = fmaf(a0, sC[d*4+3], fmaf(a1, sC[80+d*4+3], a2*sC[160+d*4+3]));
    w[0]=fmaf(c0,ad,w[0]); w[1]=fmaf(c1,ad,w[1]); w[2]=fmaf(c2,ad,w[2]); w[3]=fmaf(c3,ad,w[3]);
    G[0]=fmaf(c0,c0,G[0]); G[1]=fmaf(c0,c1,G[1]); G[2]=fmaf(c0,c2,G[2]); G[3]=fmaf(c0,c3,G[3]);
    G[4]=fmaf(c1,c1,G[4]); G[5]=fmaf(c1,c2,G[5]); G[6]=fmaf(c1,c3,G[6]);
    G[7]=fmaf(c2,c2,G[7]); G[8]=fmaf(c2,c3,G[8]);
    G[9]=fmaf(c3,c3,G[9]);
  }
  #pragma unroll
  for (int c=0;c<10;c++) G[c]*=RINV;
  #pragma unroll
  for (int c=0;c<4;c++)  w[c]*=RINV;
}

// filter element: Phi=(I+qG)^-1; A*=Phi A; b*=q Phi w; C*=q Phi; eta*=A^T Phi w; J*=A^T Phi G A
__device__ __forceinline__ void elem_build(const float* Am, const float* G, const float* w,
    float* Ae, float* be, float* Ce, float* he, float* Je)
{
  float Gf[16]; sym_expand(G,Gf);
  float N[16];
  #pragma unroll
  for (int i=0;i<16;i++) N[i] = QQ*Gf[i];
  N[0]+=1.f; N[5]+=1.f; N[10]+=1.f; N[15]+=1.f;
  float Phi[16]; inv4(N,Phi);
  mm4(Phi, Am, Ae);
  float Pw[4]; mv4(Phi, w, Pw);
  #pragma unroll
  for (int i=0;i<4;i++) be[i]=QQ*Pw[i];
  mv4_t(Am, Pw, he);
  float PhiG[16]; mm4(Phi, Gf, PhiG);
  float U[16]; mm4_at(Am, PhiG, U);
  float Jf[16]; mm4(U, Am, Jf);
  sym_from_full(Jf, Je);
  float Cf[16];
  #pragma unroll
  for (int i=0;i<16;i++) Cf[i]=QQ*Phi[i];
  sym_from_full(Cf, Ce);
}

// running(earlier, in-out) = running ⊗ e(later)
__device__ __forceinline__ void compose(float* Ar, float* br, float* Cr, float* hr, float* Jr,
    const float* Ae, const float* be, const float* Ce, const float* he, const float* Je)
{
  float Crf[16]; sym_expand(Cr,Crf);
  float Jef[16]; sym_expand(Je,Jef);
  float N[16]; mm4(Crf,Jef,N);
  N[0]+=1.f; N[5]+=1.f; N[10]+=1.f; N[15]+=1.f;
  float E[16]; inv4(N,E);
  float EA[16]; mm4(E,Ar,EA);
  float Anew[16]; mm4(Ae,EA,Anew);
  float t1[4]; mv4(Crf,he,t1);
  #pragma unroll
  for (int i=0;i<4;i++) t1[i]+=br[i];
  float t2[4]; mv4(E,t1,t2);
  float bnew[4]; mv4(Ae,t2,bnew);
  #pragma unroll
  for (int i=0;i<4;i++) bnew[i]+=be[i];
  float EC[16]; mm4(E,Crf,EC);
  float AEC[16]; mm4(Ae,EC,AEC);
  float Cfull[16]; mm4_bt(AEC,Ae,Cfull);
  float Cnew[10]; sym_from_full(Cfull,Cnew);
  #pragma unroll
  for (int i=0;i<10;i++) Cnew[i]+=Ce[i];
  float v[4]; mv4(Jef,br,v);
  #pragma unroll
  for (int i=0;i<4;i++) v[i]=he[i]-v[i];
  float Ev[4]; mv4_t(E,v,Ev);
  float hnew[4]; mv4_t(Ar,Ev,hnew);
  #pragma unroll
  for (int i=0;i<4;i++) hnew[i]+=hr[i];
  float EtJ[16]; mm4_at(E,Jef,EtJ);
  float AtEtJ[16]; mm4_at(Ar,EtJ,AtEtJ);
  float Jfull[16]; mm4(AtEtJ,Ar,Jfull);
  float Jnew[10]; sym_from_full(Jfull,Jnew);
  #pragma unroll
  for (int i=0;i<10;i++) Jnew[i]+=Jr[i];
  #pragma unroll
  for (int i=0;i<16;i++) Ar[i]=Anew[i];
  #pragma unroll
  for (int i=0;i<4;i++){ br[i]=bnew[i]; hr[i]=hnew[i]; }
  #pragma unroll
  for (int i=0;i<10;i++){ Cr[i]=Cnew[i]; Jr[i]=Jnew[i]; }
}

// apply filter element to state (m,S)
__device__ __forceinline__ void elem_apply(const float* Ae, const float* be, const float* Ce,
    const float* he, const float* Je, float* m, float* S)
{
  float Pf[16]; sym_expand(S,Pf);
  float Jf[16]; sym_expand(Je,Jf);
  float N[16]; mm4(Pf,Jf,N);
  N[0]+=1.f; N[5]+=1.f; N[10]+=1.f; N[15]+=1.f;
  float T[16]; inv4(N,T);
  float t1[4]; mv4(Pf,he,t1);
  #pragma unroll
  for (int i=0;i<4;i++) t1[i]+=m[i];
  float t2[4]; mv4(T,t1,t2);
  float mn[4]; mv4(Ae,t2,mn);
  #pragma unroll
  for (int i=0;i<4;i++) mn[i]+=be[i];
  float TP[16]; mm4(T,Pf,TP);
  float ATP[16]; mm4(Ae,TP,ATP);
  float Pn[16]; mm4_bt(ATP,Ae,Pn);
  float Sn[10]; sym_from_full(Pn,Sn);
  #pragma unroll
  for (int i=0;i<10;i++) S[i]=Sn[i]+Ce[i];
  #pragma unroll
  for (int i=0;i<4;i++) m[i]=mn[i];
}

// smoother element: D = Mj A1^T inv(Pc1); e = pzj - D (A1 pzj); F = Mj - D Pc1 D^T
__device__ __forceinline__ void sm_build(const float* A1, const float* Pc1,
    const float* Mj, const float* pzj, float* D, float* e, float* F)
{
  float Pcf[16]; sym_expand(Pc1,Pcf);
  float E[16]; inv4(Pcf,E);
  float Mf[16]; sym_expand(Mj,Mf);
  float MB[16]; mm4_bt(Mf,A1,MB);
  mm4(MB,E,D);
  float zh[4]; mv4(A1,pzj,zh);
  float Dzh[4]; mv4(D,zh,Dzh);
  #pragma unroll
  for (int i=0;i<4;i++) e[i]=pzj[i]-Dzh[i];
  float U[16]; mm4(D,Pcf,U);
  float W[16]; mm4_bt(U,D,W);
  float Ws[10]; sym_from_full(W,Ws);
  #pragma unroll
  for (int i=0;i<10;i++) F[i]=Mj[i]-Ws[i];
}

// apply smoother element: z' = D z + e; S' = D S D^T + F
__device__ __forceinline__ void sm_apply(const float* D, const float* e, const float* F,
    float* z, float* S)
{
  float zn[4]; mv4(D,z,zn);
  #pragma unroll
  for (int i=0;i<4;i++) z[i]=zn[i]+e[i];
  float Sf[16]; sym_expand(S,Sf);
  float U[16]; mm4(D,Sf,U);
  float W[16]; mm4_bt(U,D,W);
  float Sn[10]; sym_from_full(W,Sn);
  #pragma unroll
  for (int i=0;i<10;i++) S[i]=Sn[i]+F[i];
}

// affine pre-compose: running = Ek ∘ running  (Ek applied after running)
__device__ __forceinline__ void aff_pre(float* Dr, float* er, float* Fr,
    const float* Dk, const float* ek, const float* Fk)
{
  float Dn[16]; mm4(Dk,Dr,Dn);
  float t1[4]; mv4(Dk,er,t1);
  float Frf[16]; sym_expand(Fr,Frf);
  float U[16]; mm4(Dk,Frf,U);
  float W[16]; mm4_bt(U,Dk,W);
  float Ws[10]; sym_from_full(W,Ws);
  #pragma unroll
  for (int i=0;i<4;i++) er[i]=t1[i]+ek[i];
  #pragma unroll
  for (int i=0;i<10;i++) Fr[i]=Ws[i]+Fk[i];
  #pragma unroll
  for (int i=0;i<16;i++) Dr[i]=Dn[i];
}

// ===== Kernel 1: chunk composite + wave prefix scan + replay + smoother-element emission =====
// wave = batch b, lane = chunk c. Writes el (all CL slots incl. boundary) and term[b].
__global__ __launch_bounds__(256) void k_fwd(
    const float* __restrict__ a, const float* __restrict__ logits,
    const float* __restrict__ Abase, const float* __restrict__ Cbase,
    float4* __restrict__ el, float4* __restrict__ term)
{
  __shared__ float sA[KK*16];
  __shared__ float sC[KK*DA*DZ];
  __shared__ float stash[256*26];      // per-thread (A0[16], Pc0[10]) of own chunk's first step
  for (int i=threadIdx.x;i<KK*16;i+=256) sA[i]=Abase[i];
  for (int i=threadIdx.x;i<KK*DA*DZ;i+=256) sC[i]=Cbase[i];
  __syncthreads();
  int lane = threadIdx.x & 63;
  int b = blockIdx.x*4 + (threadIdx.x>>6);
  int c = lane;

  const float4* lgp = (const float4*)(logits + ((size_t)b*TT + c*CL)*KK);
  float4 lq0=lgp[0], lq1=lgp[1], lq2=lgp[2];
  float lgf[12]={lq0.x,lq0.y,lq0.z,lq0.w, lq1.x,lq1.y,lq1.z,lq1.w, lq2.x,lq2.y,lq2.z,lq2.w};
  const float4* ap = (const float4*)(a + ((size_t)b*TT + c*CL)*DA);

  // ---- Phase A: chunk composite X = A[0:16], b[16:20], C[20:30], h[30:34], J[34:44]
  float X[44];
  #pragma unroll 1
  for (int s=0;s<CL;s++){
    float4 av[5];
    #pragma unroll
    for (int i=0;i<5;i++) av[i]=ap[s*5+i];
    float Am[16], G[10], w[4];
    mix_from_regs(av, lgf[s*3+0], lgf[s*3+1], lgf[s*3+2], sA, sC, Am, G, w);
    float Ae[16], be[4], Ce[10], he[4], Je[10];
    elem_build(Am,G,w,Ae,be,Ce,he,Je);
    if (s==0){
      #pragma unroll
      for (int i=0;i<16;i++) X[i]=Ae[i];
      #pragma unroll
      for (int i=0;i<4;i++){ X[16+i]=be[i]; X[30+i]=he[i]; }
      #pragma unroll
      for (int i=0;i<10;i++){ X[20+i]=Ce[i]; X[34+i]=Je[i]; }
    } else {
      compose(X, X+16, X+20, X+30, X+34, Ae, be, Ce, he, Je);
    }
  }

  // ---- Phase B: Kogge-Stone inclusive prefix scan (non-commutative)
  #pragma unroll 1
  for (int d=1; d<NC; d<<=1){
    float P[44];
    #pragma unroll
    for (int i=0;i<44;i++) P[i] = __shfl_up(X[i], d, 64);
    if (lane >= d){
      compose(P, P+16, P+20, P+30, P+34, X, X+16, X+20, X+30, X+34);
      #pragma unroll
      for (int i=0;i<44;i++) X[i]=P[i];
    }
  }
  // exclusive shift + apply to initial state (0, 20 I) -> chunk-start state (z,S)
  float Pm[44];
  #pragma unroll
  for (int i=0;i<44;i++) Pm[i] = __shfl_up(X[i], 1, 64);
  float z[4]={0.f,0.f,0.f,0.f};
  float S[10]={20.f,0.f,0.f,0.f,20.f,0.f,0.f,20.f,0.f,20.f};
  if (lane > 0) elem_apply(Pm, Pm+16, Pm+20, Pm+30, Pm+34, z, S);

  // ---- Phase C: replay chunk; (z,S) doubles as (pz_{s-1}, M_{s-1})
  float* myst = stash + threadIdx.x*26;
  #pragma unroll 1
  for (int s=0;s<CL;s++){
    float4 av[5];
    #pragma unroll
    for (int i=0;i<5;i++) av[i]=ap[s*5+i];
    float Am[16], G[10], w[4];
    mix_from_regs(av, lgf[s*3+0], lgf[s*3+1], lgf[s*3+2], sA, sC, Am, G, w);
    float zh[4];
    mv4(Am,z,zh);
    float Sf[16]; sym_expand(S,Sf);
    float AS[16]; mm4(Am,Sf,AS);
    float P[10];
    {
      int cc=0;
      #pragma unroll
      for (int i=0;i<4;i++){
        #pragma unroll
        for (int j=0;j<4;j++){
          if (j<i) continue;
          float acc = AS[i*4+0]*Am[j*4+0];
          acc = fmaf(AS[i*4+1],Am[j*4+1],acc);
          acc = fmaf(AS[i*4+2],Am[j*4+2],acc);
          acc = fmaf(AS[i*4+3],Am[j*4+3],acc);
          if (i==j) acc += QQ;
          P[cc++] = acc;
        }
      }
    }
    float Pc[10];
    Pc[0]=fmaxf(P[0],1e-4f); Pc[1]=fmaxf(P[1],0.f); Pc[2]=fmaxf(P[2],0.f); Pc[3]=fmaxf(P[3],0.f);
    Pc[4]=fmaxf(P[4],1e-4f); Pc[5]=fmaxf(P[5],0.f); Pc[6]=fmaxf(P[6],0.f);
    Pc[7]=fmaxf(P[7],1e-4f); Pc[8]=fmaxf(P[8],0.f);
    Pc[9]=fmaxf(P[9],1e-4f);

    if (s==0){
      // stash (A0, Pc0) for lane c-1's boundary element
      #pragma unroll
      for (int i=0;i<16;i++) myst[i]=Am[i];
      #pragma unroll
      for (int i=0;i<10;i++) myst[16+i]=Pc[i];
    } else {
      // E_{t-1}: uses previous posterior (z,S) BEFORE this step's update
      float D[16], e[4], F[10];
      sm_build(Am, Pc, S, z, D, e, F);
      float4 eb[8]; float* pe2=(float*)eb;
      #pragma unroll
      for (int i=0;i<16;i++) pe2[i]=D[i];
      #pragma unroll
      for (int i=0;i<4;i++) pe2[16+i]=e[i];
      #pragma unroll
      for (int i=0;i<10;i++) pe2[20+i]=F[i];
      pe2[30]=0.f; pe2[31]=0.f;
      float4* de = el + (((size_t)b*NC + c)*CL + (s-1))*8;
      #pragma unroll
      for (int p=0;p<8;p++) de[p]=eb[p];
    }

    // posterior update
    float Pf[16]; sym_expand(P,Pf);
    float Gf[16]; sym_expand(G,Gf);
    float N[16]; mm4(Pf,Gf,N);
    N[0]+=1.f; N[5]+=1.f; N[10]+=1.f; N[15]+=1.f;
    float Ninv[16]; inv4(N,Ninv);
    float Mf[16]; mm4(Ninv,Pf,Mf);
    float M[10]; sym_from_full(Mf,M);
    float u[4];
    #pragma unroll
    for (int i=0;i<4;i++)
      u[i] = w[i] - fmaf(Gf[i*4+3],zh[3],fmaf(Gf[i*4+2],zh[2],fmaf(Gf[i*4+1],zh[1],Gf[i*4+0]*zh[0])));
    float Ms[16]; sym_expand(M,Ms);
    #pragma unroll
    for (int i=0;i<4;i++)
      z[i] = zh[i] + fmaf(Ms[i*4+3],u[3],fmaf(Ms[i*4+2],u[2],fmaf(Ms[i*4+1],u[1],Ms[i*4+0]*u[0])));
    #pragma unroll
    for (int i=0;i<10;i++) S[i]=M[i];
  }
  __syncthreads();

  if (c < NC-1){
    // boundary element E_{c*CL+CL-1} from next lane's (A0,Pc0) — same wave, same b
    const float* nst = stash + (threadIdx.x+1)*26;
    float A0[16], Pc0[10];
    #pragma unroll
    for (int i=0;i<16;i++) A0[i]=nst[i];
    #pragma unroll
    for (int i=0;i<10;i++) Pc0[i]=nst[16+i];
    float D[16], e[4], F[10];
    sm_build(A0, Pc0, S, z, D, e, F);
    float4 eb[8]; float* pe2=(float*)eb;
    #pragma unroll
    for (int i=0;i<16;i++) pe2[i]=D[i];
    #pragma unroll
    for (int i=0;i<4;i++) pe2[16+i]=e[i];
    #pragma unroll
    for (int i=0;i<10;i++) pe2[20+i]=F[i];
    pe2[30]=0.f; pe2[31]=0.f;
    float4* de = el + (((size_t)b*NC + c)*CL + (CL-1))*8;
    #pragma unroll
    for (int p=0;p<8;p++) de[p]=eb[p];
  } else {
    // terminal posterior (M,pz) at t=TT-1
    float4 tb[4]; float* pt=(float*)tb;
    #pragma unroll
    for (int i=0;i<10;i++) pt[i]=S[i];
    #pragma unroll
    for (int i=0;i<4;i++) pt[10+i]=z[i];
    pt[14]=0.f; pt[15]=0.f;
    float4* dt = term + (size_t)b*4;
    #pragma unroll
    for (int p=0;p<4;p++) dt[p]=tb[p];
  }
}

// ===== Kernel 2: per-chunk composite + wave suffix scan + apply + outputs =====
__global__ __launch_bounds__(256) void k_bwd(
    const float4* __restrict__ el, const float4* __restrict__ term,
    float* __restrict__ out)
{
  int lane = threadIdx.x & 63;
  int b = blockIdx.x*4 + (threadIdx.x>>6);
  int c = lane;
  const float4* base = el + ((size_t)b*NC + c)*CL*8;

  // ---- Phase D: chunk composite Y = D[0:16], e[16:20], F[20:30]
  float Y[30];
  int kstart;
  {
    int k0 = (c < NC-1) ? (CL-1) : (CL-2);
    float4 eb[8];
    #pragma unroll
    for (int p=0;p<8;p++) eb[p]=base[k0*8+p];
    const float* pe=(const float*)eb;
    #pragma unroll
    for (int i=0;i<30;i++) Y[i]=pe[i];
    kstart = k0-1;
  }
  #pragma unroll 1
  for (int k=kstart;k>=0;k--){
    float4 eb[8];
    #pragma unroll
    for (int p=0;p<8;p++) eb[p]=base[k*8+p];
    const float* pe=(const float*)eb;
    aff_pre(Y, Y+16, Y+20, pe, pe+16, pe+20);
  }

  // ---- Kogge-Stone suffix scan (partner from later chunks applied first)
  #pragma unroll 1
  for (int d=1; d<NC; d<<=1){
    float P[30];
    #pragma unroll
    for (int i=0;i<30;i++) P[i] = __shfl_down(Y[i], d, 64);
    if (c + d < NC){
      aff_pre(P, P+16, P+20, Y, Y+16, Y+20);
      #pragma unroll
      for (int i=0;i<30;i++) Y[i]=P[i];
    }
  }

  // terminal smoothed state = filter posterior at t=TT-1
  const float4* tp = term + (size_t)b*4;
  float4 t0=tp[0], t1q=tp[1], t2q=tp[2], t3q=tp[3];
  float S[10]={t0.x,t0.y,t0.z,t0.w, t1q.x,t1q.y,t1q.z,t1q.w, t2q.x,t2q.y};
  float z[4]={t2q.z,t2q.w,t3q.x,t3q.y};
  (void)t3q;

  // state at own chunk's top boundary
  float Pn[30];
  #pragma unroll
  for (int i=0;i<30;i++) Pn[i] = __shfl_down(Y[i], 1, 64);
  if (c < NC-1) sm_apply(Pn, Pn+16, Pn+20, z, S);

  // ---- Phase E: apply own elements, write outputs
  const size_t Z0 = (size_t)BB*TT*DZ;
  int ktop = (c==NC-1) ? (CL-2) : (CL-1);
  float4 cur[8], nxt[8];
  #pragma unroll
  for (int p=0;p<8;p++) cur[p]=base[ktop*8+p];
  if (c==NC-1){
    *(float4*)(out + ((size_t)b*TT + (TT-1))*DZ) = make_float4(z[0],z[1],z[2],z[3]);
    float Sf[16]; sym_expand(S,Sf);
    float4* so=(float4*)(out + Z0 + ((size_t)b*TT + (TT-1))*16);
    so[0]=make_float4(Sf[0],Sf[1],Sf[2],Sf[3]);
    so[1]=make_float4(Sf[4],Sf[5],Sf[6],Sf[7]);
    so[2]=make_float4(Sf[8],Sf[9],Sf[10],Sf[11]);
    so[3]=make_float4(Sf[12],Sf[13],Sf[14],Sf[15]);
  }
  #pragma unroll 1
  for (int k=ktop;k>=0;k--){
    if (k-1 >= 0){
      #pragma unroll
      for (int p=0;p<8;p++) nxt[p]=base[(k-1)*8+p];
    }
    const float* pe=(const float*)cur;
    sm_apply(pe, pe+16, pe+20, z, S);
    int j = c*CL + k;
    *(float4*)(out + ((size_t)b*TT + j)*DZ) = make_float4(z[0],z[1],z[2],z[3]);
    float Sf[16]; sym_expand(S,Sf);
    float4* so=(float4*)(out + Z0 + ((size_t)b*TT + j)*16);
    so[0]=make_float4(Sf[0],Sf[1],Sf[2],Sf[3]);
    so[1]=make_float4(Sf[4],Sf[5],Sf[6],Sf[7]);
    so[2]=make_float4(Sf[8],Sf[9],Sf[10],Sf[11]);
    so[3]=make_float4(Sf[12],Sf[13],Sf[14],Sf[15]);
    #pragma unroll
    for (int p=0;p<8;p++) cur[p]=nxt[p];
  }
}

extern "C" void kernel_launch(void* const* d_in, const int* in_sizes, int n_in,
                              void* d_out, int out_size, void* d_ws, size_t ws_size,
                              hipStream_t stream) {
  const float* a      = (const float*)d_in[0];
  const float* logits = (const float*)d_in[1];
  const float* Abase  = (const float*)d_in[2];
  const float* Cbase  = (const float*)d_in[3];
  float* out = (float*)d_out;

  float4* ws4 = (float4*)d_ws;
  float4* el   = ws4;                          // 32 f4 per (b,c)  = 67.1 MB
  float4* term = el + (size_t)CL*8*NCH;        // 4 f4 per b       = 131 KB

  k_fwd<<<dim3(BB/4), dim3(256), 0, stream>>>(a, logits, Abase, Cbase, el, term);
  k_bwd<<<dim3(BB/4), dim3(256), 0, stream>>>(el, term, out);
}